// Round 5
// baseline (472.724 us; speedup 1.0000x reference)
//
#include <hip/hip_runtime.h>
#include <hip/hip_bf16.h>

// Problem constants (AFTLocalAutoregressive): T=2048, B=2, D=512, S=32
#define TT 2048
#define BB 2
#define DD 512
#define BD (BB*DD)        // 1024 columns (b,d flattened)
#define SS 32
#define MR (TT*BB)        // 4096 GEMM rows; m = 2t + b
#define NE (TT*BB*DD)     // 2097152 elements per (T,B,D) tensor
#define CH 32             // t-chunk size for scan/window (== one 64-row m-tile)

typedef __bf16 bf16x8 __attribute__((ext_vector_type(8)));
typedef float f32x4 __attribute__((ext_vector_type(4)));
typedef float f32x2 __attribute__((ext_vector_type(2)));

__device__ __forceinline__ void async_copy16(void* lds, const void* gptr) {
    __builtin_amdgcn_global_load_lds(
        (const __attribute__((address_space(1))) void*)gptr,
        (__attribute__((address_space(3))) void*)lds,
        16, 0, 0);
}

#define MFMA16(a,b,c) __builtin_amdgcn_mfma_f32_16x16x32_bf16((a),(b),(c),0,0,0)

// Manual grid barrier (plain launch; co-residency guaranteed: 512 blocks,
// 48KB LDS -> 3/CU cap, launch_bounds(256,2) -> VGPR<=256 -> 2/CU >= grid/256).
// Release: per-wave __syncthreads drains own stores; acq_rel atomicAdd at
// agent scope writes back L2 (cross-XCD). Acquire: spin load + trailing
// all-threads threadfence invalidates L1/L2 for every wave.
__device__ __forceinline__ void grid_barrier(unsigned* ctr, unsigned target) {
    __syncthreads();
    if (threadIdx.x == 0) {
        __hip_atomic_fetch_add(ctr, 1u, __ATOMIC_ACQ_REL, __HIP_MEMORY_SCOPE_AGENT);
        while (__hip_atomic_load(ctr, __ATOMIC_ACQUIRE, __HIP_MEMORY_SCOPE_AGENT) < target) {
            __builtin_amdgcn_s_sleep(2);
        }
    }
    __syncthreads();
    __threadfence();
}

// ---------------------------------------------------------------------------
// Single kernel: P1 cast -> P2 qkv GEMMs -> P3 scan+window -> P4 out GEMM,
// separated by manual grid barriers.  Grid 512 x 256, all blocks co-resident.
// Eliminates 4 inter-dispatch gaps + scan_part dispatch + pref buffer.
// ---------------------------------------------------------------------------
__global__ __launch_bounds__(256, 2) void aft_mega(
    const float* __restrict__ query, const float* __restrict__ key,
    const float* __restrict__ value,
    const float* __restrict__ Wq, const float* __restrict__ bq,
    const float* __restrict__ Wk, const float* __restrict__ bk,
    const float* __restrict__ Wv, const float* __restrict__ bv,
    const float* __restrict__ pb,
    const float* __restrict__ Wo, const float* __restrict__ bo,
    float* __restrict__ out,
    float* __restrict__ qf, float* __restrict__ ekn, float* __restrict__ part,
    __hip_bfloat16* __restrict__ qb, __hip_bfloat16* __restrict__ kb,
    __hip_bfloat16* __restrict__ vb, __hip_bfloat16* __restrict__ yb,
    __hip_bfloat16* __restrict__ Wqb, __hip_bfloat16* __restrict__ Wkb,
    __hip_bfloat16* __restrict__ Wvb, __hip_bfloat16* __restrict__ Wob,
    unsigned* bar)
{
    __shared__ char smem[49152];
    const int tid = threadIdx.x;
    const int bid = blockIdx.x;          // 0..511
    const int lane = tid & 63;
    const int wv = tid >> 6;

    // ================= P1: fp32 -> bf16 cast (grid-stride) =================
    // 1835008 float4 units = 14 passes x 512 blk x 256 thr; batches of 7 so
    // 7 independent loads are in flight before any store.
    {
        #pragma unroll
        for (int h = 0; h < 2; ++h) {
            float4 f[7];
            unsigned short* da[7];
            #pragma unroll
            for (int p = 0; p < 7; ++p) {
                int u = (h * 7 + p) * 131072 + bid * 256 + tid;
                const float* s; __hip_bfloat16* d; size_t i;
                if (u < 1572864) {
                    int which = u >> 19;              // 524288 units each
                    s = which == 0 ? query : (which == 1 ? key : value);
                    d = which == 0 ? qb : (which == 1 ? kb : vb);
                    i = (size_t)(u & 524287) * 4;
                } else {
                    int u2 = u - 1572864;
                    int which = u2 >> 16;             // 65536 units each
                    s = which == 0 ? Wq : (which == 1 ? Wk : (which == 2 ? Wv : Wo));
                    d = which == 0 ? Wqb : (which == 1 ? Wkb : (which == 2 ? Wvb : Wob));
                    i = (size_t)(u2 & 65535) * 4;
                }
                f[p] = *(const float4*)(s + i);
                da[p] = (unsigned short*)d + i;
            }
            #pragma unroll
            for (int p = 0; p < 7; ++p) {
                union { __hip_bfloat16 hh[4]; ushort4 u4; } cv;
                cv.hh[0] = __float2bfloat16(f[p].x); cv.hh[1] = __float2bfloat16(f[p].y);
                cv.hh[2] = __float2bfloat16(f[p].z); cv.hh[3] = __float2bfloat16(f[p].w);
                *(ushort4*)da[p] = cv.u4;
            }
        }
    }
    grid_barrier(&bar[0], 512);

    // ================= P2: q/k/v projections (one block = one 64x64 tile,
    // K,V fused then Q) =================
    {
        const int wave_m = wv >> 1, wave_n = wv & 1;
        const int kq = lane >> 4, rr = lane & 15;
        const int n0 = (bid & 7) * 64, m0 = (bid >> 3) * 64;

        // ---- K,V fused GEMM + exp epilogue + per-chunk column sums ----
        {
            f32x4 acck[2][2] = {}, accv[2][2] = {};
            const __hip_bfloat16* AKrow = kb + (size_t)(m0 + lane) * DD + wv * 8;
            const __hip_bfloat16* WKrow = Wkb + (size_t)(n0 + lane) * DD + wv * 8;
            const __hip_bfloat16* AVrow = vb + (size_t)(m0 + lane) * DD + wv * 8;
            const __hip_bfloat16* WVrow = Wvb + (size_t)(n0 + lane) * DD + wv * 8;
            #pragma unroll
            for (int pt = 0; pt < 2; ++pt) {
                char* nb = smem + pt * 16384;
                async_copy16(nb +         wv*1024, AKrow + pt*32);
                async_copy16(nb +  4096 + wv*1024, WKrow + pt*32);
                async_copy16(nb +  8192 + wv*1024, AVrow + pt*32);
                async_copy16(nb + 12288 + wv*1024, WVrow + pt*32);
            }
            asm volatile("s_waitcnt vmcnt(4)" ::: "memory");   // tile 0 landed
            __builtin_amdgcn_s_barrier();
            #pragma unroll
            for (int it = 0; it < 16; ++it) {
                if (it + 2 < 16) {
                    char* nb = smem + ((it + 2) % 3) * 16384;
                    async_copy16(nb +         wv*1024, AKrow + (it+2)*32);
                    async_copy16(nb +  4096 + wv*1024, WKrow + (it+2)*32);
                    async_copy16(nb +  8192 + wv*1024, AVrow + (it+2)*32);
                    async_copy16(nb + 12288 + wv*1024, WVrow + (it+2)*32);
                }
                const char* cb = smem + (it % 3) * 16384;
                bf16x8 ak0 = *(const bf16x8*)(cb +         kq*1024 + (wave_m*32 +  0 + rr)*16);
                bf16x8 ak1 = *(const bf16x8*)(cb +         kq*1024 + (wave_m*32 + 16 + rr)*16);
                bf16x8 bk0 = *(const bf16x8*)(cb +  4096 + kq*1024 + (wave_n*32 +  0 + rr)*16);
                bf16x8 bk1 = *(const bf16x8*)(cb +  4096 + kq*1024 + (wave_n*32 + 16 + rr)*16);
                bf16x8 av0 = *(const bf16x8*)(cb +  8192 + kq*1024 + (wave_m*32 +  0 + rr)*16);
                bf16x8 av1 = *(const bf16x8*)(cb +  8192 + kq*1024 + (wave_m*32 + 16 + rr)*16);
                bf16x8 bv0 = *(const bf16x8*)(cb + 12288 + kq*1024 + (wave_n*32 +  0 + rr)*16);
                bf16x8 bv1 = *(const bf16x8*)(cb + 12288 + kq*1024 + (wave_n*32 + 16 + rr)*16);
                acck[0][0] = MFMA16(ak0, bk0, acck[0][0]);
                acck[0][1] = MFMA16(ak0, bk1, acck[0][1]);
                acck[1][0] = MFMA16(ak1, bk0, acck[1][0]);
                acck[1][1] = MFMA16(ak1, bk1, acck[1][1]);
                accv[0][0] = MFMA16(av0, bv0, accv[0][0]);
                accv[0][1] = MFMA16(av0, bv1, accv[0][1]);
                accv[1][0] = MFMA16(av1, bv0, accv[1][0]);
                accv[1][1] = MFMA16(av1, bv1, accv[1][1]);
                if (it < 15) {
                    if (it < 14) asm volatile("s_waitcnt vmcnt(4) lgkmcnt(0)" ::: "memory");
                    else         asm volatile("s_waitcnt vmcnt(0) lgkmcnt(0)" ::: "memory");
                    __builtin_amdgcn_s_barrier();
                }
            }
            // epilogue: interleaved ekn stores + per-chunk column sums (b = r&1)
            float sd[2][2] = {{0.f,0.f},{0.f,0.f}};
            float sn[2][2] = {{0.f,0.f},{0.f,0.f}};
            #pragma unroll
            for (int ms = 0; ms < 2; ++ms)
                #pragma unroll
                for (int ns = 0; ns < 2; ++ns) {
                    int n = n0 + wave_n*32 + ns*16 + rr;
                    float bkn = bk[n], bvn = bv[n];
                    #pragma unroll
                    for (int r = 0; r < 4; ++r) {
                        int m = m0 + wave_m*32 + ms*16 + kq*4 + r;
                        float e  = expf(acck[ms][ns][r] + bkn);
                        float nv = e * (accv[ms][ns][r] + bvn);
                        float2 st; st.x = e; st.y = nv;
                        *(float2*)&ekn[((size_t)m * DD + n) * 2] = st;
                        sd[ns][r & 1] += e;
                        sn[ns][r & 1] += nv;
                    }
                }
            #pragma unroll
            for (int ns = 0; ns < 2; ++ns)
                #pragma unroll
                for (int par = 0; par < 2; ++par) {
                    sd[ns][par] += __shfl_xor(sd[ns][par], 16, 64);
                    sd[ns][par] += __shfl_xor(sd[ns][par], 32, 64);
                    sn[ns][par] += __shfl_xor(sn[ns][par], 16, 64);
                    sn[ns][par] += __shfl_xor(sn[ns][par], 32, 64);
                }
            __syncthreads();                       // smem free for reuse
            float* red = (float*)smem;             // red[which(4)][wave_m(2)][64]
            if (lane < 16) {
                #pragma unroll
                for (int ns = 0; ns < 2; ++ns) {
                    int c2 = wave_n*32 + ns*16 + rr;
                    red[(0*2 + wave_m)*64 + c2] = sd[ns][0];
                    red[(1*2 + wave_m)*64 + c2] = sd[ns][1];
                    red[(2*2 + wave_m)*64 + c2] = sn[ns][0];
                    red[(3*2 + wave_m)*64 + c2] = sn[ns][1];
                }
            }
            __syncthreads();
            {
                int which = tid >> 6;              // 0: d,b0  1: d,b1  2: n,b0  3: n,b1
                int c2 = tid & 63;
                float s = red[(which*2 + 0)*64 + c2] + red[(which*2 + 1)*64 + c2];
                int b = which & 1;
                int sel = which >> 1;              // 0 = den, 1 = num
                part[((size_t)(bid >> 3) * BD + b*512 + n0 + c2) * 2 + sel] = s;
            }
        }
        __syncthreads();                           // smem reuse boundary

        // ---- Q projection ----
        {
            f32x4 acc[2][2] = {};
            const __hip_bfloat16* Arow = qb + (size_t)(m0 + lane) * DD + wv * 8;
            const __hip_bfloat16* Wrow = Wqb + (size_t)(n0 + lane) * DD + wv * 8;
            async_copy16(smem + 0*8192 +        wv*1024, Arow + 0);
            async_copy16(smem + 0*8192 + 4096 + wv*1024, Wrow + 0);
            async_copy16(smem + 1*8192 +        wv*1024, Arow + 32);
            async_copy16(smem + 1*8192 + 4096 + wv*1024, Wrow + 32);
            asm volatile("s_waitcnt vmcnt(2)" ::: "memory");
            __builtin_amdgcn_s_barrier();
            #pragma unroll
            for (int it = 0; it < 16; ++it) {
                if (it + 2 < 16) {
                    char* nb = smem + ((it + 2) % 3) * 8192;
                    async_copy16(nb +        wv*1024, Arow + (it+2)*32);
                    async_copy16(nb + 4096 + wv*1024, Wrow + (it+2)*32);
                }
                const char* cb = smem + (it % 3) * 8192;
                bf16x8 a0 = *(const bf16x8*)(cb + kq*1024 + (wave_m*32 +  0 + rr)*16);
                bf16x8 a1 = *(const bf16x8*)(cb + kq*1024 + (wave_m*32 + 16 + rr)*16);
                bf16x8 w0 = *(const bf16x8*)(cb + 4096 + kq*1024 + (wave_n*32 +  0 + rr)*16);
                bf16x8 w1 = *(const bf16x8*)(cb + 4096 + kq*1024 + (wave_n*32 + 16 + rr)*16);
                acc[0][0] = MFMA16(a0, w0, acc[0][0]);
                acc[0][1] = MFMA16(a0, w1, acc[0][1]);
                acc[1][0] = MFMA16(a1, w0, acc[1][0]);
                acc[1][1] = MFMA16(a1, w1, acc[1][1]);
                if (it < 15) {
                    if (it < 14) asm volatile("s_waitcnt vmcnt(2) lgkmcnt(0)" ::: "memory");
                    else         asm volatile("s_waitcnt vmcnt(0) lgkmcnt(0)" ::: "memory");
                    __builtin_amdgcn_s_barrier();
                }
            }
            #pragma unroll
            for (int ms = 0; ms < 2; ++ms)
                #pragma unroll
                for (int ns = 0; ns < 2; ++ns) {
                    int n = n0 + wave_n*32 + ns*16 + rr;
                    float bn = bq[n];
                    #pragma unroll
                    for (int r = 0; r < 4; ++r) {
                        int m = m0 + wave_m*32 + ms*16 + kq*4 + r;
                        qf[(size_t)m * DD + n] = acc[ms][ns][r] + bn;
                    }
                }
        }
    }
    grid_barrier(&bar[1], 512);

    // ================= P3: scan (inline) + sliding window =================
    // 1024 tiles (16 col-blocks x 64 chunks), 2 per block.  Stage E rows
    // t0-32..t0+31 (64 cols f32x2) into LDS via global_load_lds; build wl;
    // reduce part[p<chunk] inline (wave sg covers p = sg+4j); one
    // __syncthreads drains all; then per-thread 39-entry register ring.
    {
        float* Et = (float*)smem;              // 32 KB [u][c] f32x2
        float* wl = (float*)(smem + 32768);    // 4 KB  [CH][SS]
        float* red = (float*)(smem + 36864);   // 2 KB  [4][64] f32x2
        const int c = tid & 63;
        const int sg = tid >> 6;               // wave = s-group
        const int s0 = sg * 8;

        #pragma unroll
        for (int ti = 0; ti < 2; ++ti) {
            const int tile = bid + ti * 512;
            const int chunk = tile >> 4;
            const int t0 = chunk * CH;
            const int col0 = (tile & 15) * 64;
            __syncthreads();                   // previous tile's Et/red reads done

            // Stage E tile: thread covers 16B (2 cols) of row u = (tid>>5)+j*8
            {
                const int cp = tid & 31;       // col-pair
                #pragma unroll
                for (int j = 0; j < 8; ++j) {
                    int u = (tid >> 5) + j * 8;
                    int t = t0 - 32 + u;
                    if (t >= 0) {              // wave-uniform (chunk==0: skips j<4)
                        const void* g = (const void*)(ekn + ((size_t)t * BD + col0 + cp * 2) * 2);
                        async_copy16((char*)Et + wv * 1024 + j * 4096, g);
                    }
                }
                if (chunk == 0) {              // zero rows 0..31 (t<0)
                    f32x4 z = {0.f, 0.f, 0.f, 0.f};
                    #pragma unroll
                    for (int j = 0; j < 4; ++j)
                        *(f32x4*)((char*)Et + tid * 16 + j * 4096) = z;
                }
            }

            // wl[t_local][j] = valid * exp(pb[t, t-31+j])
            #pragma unroll
            for (int i = 0; i < (CH * SS) / 256; ++i) {
                int idx = tid + i * 256;
                int tl = idx >> 5, jj = idx & 31;
                int t = t0 + tl;
                int u2 = t - (SS - 1) + jj;
                float w = 0.f;
                if (u2 >= 0) w = expf(pb[(size_t)t * TT + u2]);
                wl[tl * SS + jj] = w;
            }

            // qv + inline chunk-prefix partial (wave sg covers p = sg + 4j)
            float qv[8];
            #pragma unroll
            for (int k = 0; k < 8; ++k)
                qv[k] = qf[(size_t)(t0 + s0 + k) * BD + col0 + c];
            f32x2 acc2 = {0.f, 0.f};
            #pragma unroll
            for (int j = 0; j < 16; ++j) {
                int p = sg + 4 * j;
                if (p < chunk)                 // wave-uniform predicate
                    acc2 += *(const f32x2*)&part[((size_t)p * BD + col0 + c) * 2];
            }
            *(f32x2*)&red[(sg * 64 + c) * 2] = acc2;

            __syncthreads();                   // drains copies + wl + red

            f32x2 P = *(const f32x2*)&red[(0 * 64 + c) * 2];
            P += *(const f32x2*)&red[(1 * 64 + c) * 2];
            P += *(const f32x2*)&red[(2 * 64 + c) * 2];
            P += *(const f32x2*)&red[(3 * 64 + c) * 2];

            // Pull rows s0+1 .. s0+39 once into registers
            f32x2 ring[39];
            #pragma unroll
            for (int i = 0; i < 39; ++i)
                ring[i] = *(const f32x2*)&Et[((s0 + 1 + i) * 64 + c) * 2];

            // cs(s0) = P - sum_{u=s0+1}^{31} E[u]
            f32x2 cs = P;
            #pragma unroll
            for (int u = 0; u < 31; ++u)
                if (u >= s0) cs -= ring[u - s0];

            #pragma unroll
            for (int k = 0; k < 8; ++k) {
                int s = s0 + k;
                if (k > 0) cs += ring[k - 1];
                f32x2 acc = cs;
                #pragma unroll
                for (int j4 = 0; j4 < 8; ++j4) {
                    float4 w4 = *(const float4*)&wl[s * SS + j4 * 4];
                    acc += w4.x * ring[k + j4*4 + 0];
                    acc += w4.y * ring[k + j4*4 + 1];
                    acc += w4.z * ring[k + j4*4 + 2];
                    acc += w4.w * ring[k + j4*4 + 3];
                }
                float sig = 1.f / (1.f + expf(-qv[k]));
                yb[(size_t)(t0 + s) * BD + col0 + c] = __float2bfloat16(sig * acc.y / acc.x);
            }
        }
    }
    grid_barrier(&bar[2], 512);

    // ================= P4: out = yb@Wo^T + bo =================
    {
        const int wave_m = wv >> 1, wave_n = wv & 1;
        const int kq = lane >> 4, rr = lane & 15;
        const int n0 = (bid & 7) * 64, m0 = (bid >> 3) * 64;

        f32x4 acc[2][2] = {};
        const __hip_bfloat16* Arow = yb + (size_t)(m0 + lane) * DD + wv * 8;
        const __hip_bfloat16* Wrow = Wob + (size_t)(n0 + lane) * DD + wv * 8;

        async_copy16(smem + 0*8192 +        wv*1024, Arow + 0);
        async_copy16(smem + 0*8192 + 4096 + wv*1024, Wrow + 0);
        async_copy16(smem + 1*8192 +        wv*1024, Arow + 32);
        async_copy16(smem + 1*8192 + 4096 + wv*1024, Wrow + 32);
        asm volatile("s_waitcnt vmcnt(2)" ::: "memory");
        __builtin_amdgcn_s_barrier();
        #pragma unroll
        for (int it = 0; it < 16; ++it) {
            if (it + 2 < 16) {
                char* nb = smem + ((it + 2) % 3) * 8192;
                async_copy16(nb +        wv*1024, Arow + (it+2)*32);
                async_copy16(nb + 4096 + wv*1024, Wrow + (it+2)*32);
            }
            const char* cb = smem + (it % 3) * 8192;
            bf16x8 a0 = *(const bf16x8*)(cb + kq*1024 + (wave_m*32 +  0 + rr)*16);
            bf16x8 a1 = *(const bf16x8*)(cb + kq*1024 + (wave_m*32 + 16 + rr)*16);
            bf16x8 w0 = *(const bf16x8*)(cb + 4096 + kq*1024 + (wave_n*32 +  0 + rr)*16);
            bf16x8 w1 = *(const bf16x8*)(cb + 4096 + kq*1024 + (wave_n*32 + 16 + rr)*16);
            acc[0][0] = MFMA16(a0, w0, acc[0][0]);
            acc[0][1] = MFMA16(a0, w1, acc[0][1]);
            acc[1][0] = MFMA16(a1, w0, acc[1][0]);
            acc[1][1] = MFMA16(a1, w1, acc[1][1]);
            if (it < 15) {
                if (it < 14) asm volatile("s_waitcnt vmcnt(2) lgkmcnt(0)" ::: "memory");
                else         asm volatile("s_waitcnt vmcnt(0) lgkmcnt(0)" ::: "memory");
                __builtin_amdgcn_s_barrier();
            }
        }
        #pragma unroll
        for (int ms = 0; ms < 2; ++ms)
            #pragma unroll
            for (int ns = 0; ns < 2; ++ns) {
                int n = n0 + wave_n*32 + ns*16 + rr;
                float bn = bo[n];
                #pragma unroll
                for (int r = 0; r < 4; ++r) {
                    int m = m0 + wave_m*32 + ms*16 + kq*4 + r;
                    out[(size_t)m * DD + n] = acc[ms][ns][r] + bn;
                }
            }
    }
}

extern "C" void kernel_launch(void* const* d_in, const int* in_sizes, int n_in,
                              void* d_out, int out_size, void* d_ws, size_t ws_size,
                              hipStream_t stream) {
    const float* query = (const float*)d_in[0];
    const float* key   = (const float*)d_in[1];
    const float* value = (const float*)d_in[2];
    const float* Wq    = (const float*)d_in[3];
    const float* bq    = (const float*)d_in[4];
    const float* Wk    = (const float*)d_in[5];
    const float* bk    = (const float*)d_in[6];
    const float* Wv    = (const float*)d_in[7];
    const float* bv    = (const float*)d_in[8];
    const float* pb    = (const float*)d_in[9];
    const float* Wo    = (const float*)d_in[10];
    const float* bo    = (const float*)d_in[11];
    float* out = (float*)d_out;

    float* ws = (float*)d_ws;
    float* qf   = ws;                         // NE
    float* ekn  = ws + (size_t)NE;            // 2*NE (interleaved {den,num})
    float* part = ws + (size_t)3 * NE;        // 2*64*1024 = 131072
    __hip_bfloat16* bfb = (__hip_bfloat16*)(part + 131072);
    __hip_bfloat16* qb  = bfb;                // NE each
    __hip_bfloat16* kb  = bfb + (size_t)NE;
    __hip_bfloat16* vb  = bfb + (size_t)2 * NE;
    __hip_bfloat16* yb  = bfb + (size_t)3 * NE;
    __hip_bfloat16* Wqb = bfb + (size_t)4 * NE;   // 262144 each
    __hip_bfloat16* Wkb = Wqb + 262144;
    __hip_bfloat16* Wvb = Wkb + 262144;
    __hip_bfloat16* Wob = Wvb + 262144;
    unsigned* bar = (unsigned*)(Wob + 262144);    // 3 barrier counters

    hipMemsetAsync(bar, 0, 64, stream);

    aft_mega<<<512, 256, 0, stream>>>(
        query, key, value, Wq, bq, Wk, bk, Wv, bv, pb, Wo, bo,
        out, qf, ekn, part,
        qb, kb, vb, yb, Wqb, Wkb, Wvb, Wob, bar);
}

// Round 6
// 216.948 us; speedup vs baseline: 2.1790x; 2.1790x over previous
//
#include <hip/hip_runtime.h>
#include <hip/hip_bf16.h>

// Problem constants (AFTLocalAutoregressive): T=2048, B=2, D=512, S=32
#define TT 2048
#define BB 2
#define DD 512
#define BD (BB*DD)        // 1024 columns (b,d flattened)
#define SS 32
#define MR (TT*BB)        // 4096 GEMM rows; m = 2t + b
#define NE (TT*BB*DD)     // 2097152 elements per (T,B,D) tensor
#define CH 32             // t-chunk size for scan/window (== one 64-row m-tile)

typedef __bf16 bf16x8 __attribute__((ext_vector_type(8)));
typedef short short8 __attribute__((ext_vector_type(8)));
typedef float f32x4 __attribute__((ext_vector_type(4)));
typedef float f32x2 __attribute__((ext_vector_type(2)));

__device__ __forceinline__ void async_copy16(void* lds, const void* gptr) {
    __builtin_amdgcn_global_load_lds(
        (const __attribute__((address_space(1))) void*)gptr,
        (__attribute__((address_space(3))) void*)lds,
        16, 0, 0);
}

#define MFMA16(a,b,c) __builtin_amdgcn_mfma_f32_16x16x32_bf16((a),(b),(c),0,0,0)

// 8 fp32 -> 8 bf16 (RNE) -> one 16B LDS store
__device__ __forceinline__ void cvt_store16(void* dst, float4 a, float4 b) {
    union { __hip_bfloat16 h[8]; short8 s; } u;
    u.h[0] = __float2bfloat16(a.x); u.h[1] = __float2bfloat16(a.y);
    u.h[2] = __float2bfloat16(a.z); u.h[3] = __float2bfloat16(a.w);
    u.h[4] = __float2bfloat16(b.x); u.h[5] = __float2bfloat16(b.y);
    u.h[6] = __float2bfloat16(b.z); u.h[7] = __float2bfloat16(b.w);
    *(short8*)dst = u.s;
}

// ---------------------------------------------------------------------------
// z=0: qsig = sigmoid(query@Wq^T + bq)  (fp32 out; sigmoid folded in)
// z=1: k,v projections fused; epilogue writes interleaved ekn = {ek, ek*v}
//      AND per-chunk column sums part.
// fp32 inputs are read directly and converted to bf16 in-register during LDS
// staging (cast_all eliminated).  2-buffer reg-staged pipeline, one
// __syncthreads per K-step (compiler inserts the vmcnt waits on reg use);
// global loads for tile t+2 issued while tile t computes -> latency hidden
// by the MFMA phase + 4 blocks/CU TLP.
// ---------------------------------------------------------------------------
__global__ __launch_bounds__(256) void gemm_qkv(
    const float* __restrict__ query, const float* __restrict__ key,
    const float* __restrict__ value,
    const float* __restrict__ Wq, const float* __restrict__ Wk,
    const float* __restrict__ Wv,
    const float* __restrict__ bq, const float* __restrict__ bk,
    const float* __restrict__ bv,
    float* __restrict__ qout, float* __restrict__ ekn,
    float* __restrict__ part)
{
    __shared__ char smem[32768];
    const int tid = threadIdx.x;
    const int lane = tid & 63;
    const int wv = tid >> 6;
    const int wave_m = wv >> 1, wave_n = wv & 1;
    const int m0 = blockIdx.y * 64, n0 = blockIdx.x * 64;
    const int kq = lane >> 4, rr = lane & 15;
    char* const wr = smem + wv * 1024 + lane * 16;  // thread's ds dest in a slot

    if (blockIdx.z == 0) {
        const float* A = query + (size_t)(m0 + lane) * DD + wv * 8;
        const float* W = Wq    + (size_t)(n0 + lane) * DD + wv * 8;
        f32x4 acc[2][2] = {};
        float4 a0, a1, w0, w1;
#define LD0(t) { a0 = *(const float4*)(A + (t)*32); a1 = *(const float4*)(A + (t)*32 + 4); \
                 w0 = *(const float4*)(W + (t)*32); w1 = *(const float4*)(W + (t)*32 + 4); }
#define ST0(b) { cvt_store16(wr + (b)*8192, a0, a1); cvt_store16(wr + (b)*8192 + 4096, w0, w1); }
        LD0(0); ST0(0); LD0(1);
        __syncthreads();
        #pragma unroll
        for (int it = 0; it < 16; ++it) {
            const char* cb = smem + (it & 1) * 8192;
            bf16x8 fa0 = *(const bf16x8*)(cb + kq*1024 + (wave_m*32 +  0 + rr)*16);
            bf16x8 fa1 = *(const bf16x8*)(cb + kq*1024 + (wave_m*32 + 16 + rr)*16);
            bf16x8 fw0 = *(const bf16x8*)(cb + 4096 + kq*1024 + (wave_n*32 +  0 + rr)*16);
            bf16x8 fw1 = *(const bf16x8*)(cb + 4096 + kq*1024 + (wave_n*32 + 16 + rr)*16);
            acc[0][0] = MFMA16(fa0, fw0, acc[0][0]);
            acc[0][1] = MFMA16(fa0, fw1, acc[0][1]);
            acc[1][0] = MFMA16(fa1, fw0, acc[1][0]);
            acc[1][1] = MFMA16(fa1, fw1, acc[1][1]);
            if (it + 1 < 16) ST0((it + 1) & 1);
            if (it + 2 < 16) LD0(it + 2);
            if (it < 15) __syncthreads();
        }
        #pragma unroll
        for (int ms = 0; ms < 2; ++ms)
            #pragma unroll
            for (int ns = 0; ns < 2; ++ns) {
                int n = n0 + wave_n*32 + ns*16 + rr;
                float bn = bq[n];
                #pragma unroll
                for (int r = 0; r < 4; ++r) {
                    int m = m0 + wave_m*32 + ms*16 + kq*4 + r;
                    float x = acc[ms][ns][r] + bn;
                    qout[(size_t)m * DD + n] = 1.f / (1.f + expf(-x));  // sigmoid folded
                }
            }
    } else {
        const float* AK = key   + (size_t)(m0 + lane) * DD + wv * 8;
        const float* WK = Wk    + (size_t)(n0 + lane) * DD + wv * 8;
        const float* AV = value + (size_t)(m0 + lane) * DD + wv * 8;
        const float* WV = Wv    + (size_t)(n0 + lane) * DD + wv * 8;
        f32x4 acck[2][2] = {}, accv[2][2] = {};
        float4 ak0, ak1, wk0, wk1, av0, av1, wv0, wv1;
#define LD1(t) { ak0 = *(const float4*)(AK + (t)*32); ak1 = *(const float4*)(AK + (t)*32 + 4); \
                 wk0 = *(const float4*)(WK + (t)*32); wk1 = *(const float4*)(WK + (t)*32 + 4); \
                 av0 = *(const float4*)(AV + (t)*32); av1 = *(const float4*)(AV + (t)*32 + 4); \
                 wv0 = *(const float4*)(WV + (t)*32); wv1 = *(const float4*)(WV + (t)*32 + 4); }
#define ST1(b) { cvt_store16(wr + (b)*16384,         ak0, ak1); \
                 cvt_store16(wr + (b)*16384 +  4096, wk0, wk1); \
                 cvt_store16(wr + (b)*16384 +  8192, av0, av1); \
                 cvt_store16(wr + (b)*16384 + 12288, wv0, wv1); }
        LD1(0); ST1(0); LD1(1);
        __syncthreads();
        #pragma unroll
        for (int it = 0; it < 16; ++it) {
            const char* cb = smem + (it & 1) * 16384;
            bf16x8 fk0 = *(const bf16x8*)(cb +         kq*1024 + (wave_m*32 +  0 + rr)*16);
            bf16x8 fk1 = *(const bf16x8*)(cb +         kq*1024 + (wave_m*32 + 16 + rr)*16);
            bf16x8 gk0 = *(const bf16x8*)(cb +  4096 + kq*1024 + (wave_n*32 +  0 + rr)*16);
            bf16x8 gk1 = *(const bf16x8*)(cb +  4096 + kq*1024 + (wave_n*32 + 16 + rr)*16);
            bf16x8 fv0 = *(const bf16x8*)(cb +  8192 + kq*1024 + (wave_m*32 +  0 + rr)*16);
            bf16x8 fv1 = *(const bf16x8*)(cb +  8192 + kq*1024 + (wave_m*32 + 16 + rr)*16);
            bf16x8 gv0 = *(const bf16x8*)(cb + 12288 + kq*1024 + (wave_n*32 +  0 + rr)*16);
            bf16x8 gv1 = *(const bf16x8*)(cb + 12288 + kq*1024 + (wave_n*32 + 16 + rr)*16);
            acck[0][0] = MFMA16(fk0, gk0, acck[0][0]);
            acck[0][1] = MFMA16(fk0, gk1, acck[0][1]);
            acck[1][0] = MFMA16(fk1, gk0, acck[1][0]);
            acck[1][1] = MFMA16(fk1, gk1, acck[1][1]);
            accv[0][0] = MFMA16(fv0, gv0, accv[0][0]);
            accv[0][1] = MFMA16(fv0, gv1, accv[0][1]);
            accv[1][0] = MFMA16(fv1, gv0, accv[1][0]);
            accv[1][1] = MFMA16(fv1, gv1, accv[1][1]);
            if (it + 1 < 16) ST1((it + 1) & 1);
            if (it + 2 < 16) LD1(it + 2);
            if (it < 15) __syncthreads();
        }
        // epilogue: interleaved ekn stores + per-chunk column sums (b = r&1)
        float sd[2][2] = {{0.f,0.f},{0.f,0.f}};   // [ns][parity]
        float sn[2][2] = {{0.f,0.f},{0.f,0.f}};
        #pragma unroll
        for (int ms = 0; ms < 2; ++ms)
            #pragma unroll
            for (int ns = 0; ns < 2; ++ns) {
                int n = n0 + wave_n*32 + ns*16 + rr;
                float bkn = bk[n], bvn = bv[n];
                #pragma unroll
                for (int r = 0; r < 4; ++r) {
                    int m = m0 + wave_m*32 + ms*16 + kq*4 + r;
                    float e  = expf(acck[ms][ns][r] + bkn);
                    float nv = e * (accv[ms][ns][r] + bvn);
                    float2 st; st.x = e; st.y = nv;
                    *(float2*)&ekn[((size_t)m * DD + n) * 2] = st;
                    sd[ns][r & 1] += e;
                    sn[ns][r & 1] += nv;
                }
            }
        #pragma unroll
        for (int ns = 0; ns < 2; ++ns)
            #pragma unroll
            for (int par = 0; par < 2; ++par) {
                sd[ns][par] += __shfl_xor(sd[ns][par], 16, 64);
                sd[ns][par] += __shfl_xor(sd[ns][par], 32, 64);
                sn[ns][par] += __shfl_xor(sn[ns][par], 16, 64);
                sn[ns][par] += __shfl_xor(sn[ns][par], 32, 64);
            }
        __syncthreads();                       // smem free for reuse
        float* red = (float*)smem;             // red[which(4)][wave_m(2)][64]
        if (lane < 16) {
            #pragma unroll
            for (int ns = 0; ns < 2; ++ns) {
                int c2 = wave_n*32 + ns*16 + rr;
                red[(0*2 + wave_m)*64 + c2] = sd[ns][0];
                red[(1*2 + wave_m)*64 + c2] = sd[ns][1];
                red[(2*2 + wave_m)*64 + c2] = sn[ns][0];
                red[(3*2 + wave_m)*64 + c2] = sn[ns][1];
            }
        }
        __syncthreads();
        {
            int which = tid >> 6;              // 0: d,b0  1: d,b1  2: n,b0  3: n,b1
            int c2 = tid & 63;
            float s = red[(which*2 + 0)*64 + c2] + red[(which*2 + 1)*64 + c2];
            int b = which & 1;
            int sel = which >> 1;              // 0 = den, 1 = num
            part[((size_t)blockIdx.y * BD + b*512 + n0 + c2) * 2 + sel] = s;
        }
    }
}

// ---------------------------------------------------------------------------
// fused_window: LDS-staged E-tile + inline chunk-prefix reduction + register
// window ring.  Grid (BD/64, T/CH) = (16, 64) = 1024 blocks, 4 blocks/CU.
// Block handles 64 cols x 32 t.  E rows t0-32..t0+31 staged via
// global_load_lds; part[p<chunk] reduced inline (wave sg covers p = sg+4j,
// <=16 L2 loads); one __syncthreads drains all; per-thread 39-entry f32x2
// register ring, static indices only.  qf already holds sigmoid(q).
// (Structure verified correct in rounds 3 and 5.)
// ---------------------------------------------------------------------------
__global__ __launch_bounds__(256, 3) void fused_window(
    const float* __restrict__ qf, const float* __restrict__ ekn,
    const float* __restrict__ part, const float* __restrict__ pb,
    __hip_bfloat16* __restrict__ yb)
{
    __shared__ float Et[64 * 64 * 2];     // 32 KB: [u][c] f32x2
    __shared__ float wl[CH][SS];          // 4 KB
    __shared__ float red[4 * 64 * 2];     // 2 KB
    const int tid = threadIdx.x;
    const int chunk = blockIdx.y;
    const int t0 = chunk * CH;
    const int col0 = blockIdx.x * 64;
    const int c = tid & 63;
    const int sg = tid >> 6;              // wave = s-group
    const int s0 = sg * 8;

    // Stage E tile: thread covers 16B (2 cols) of row u = (tid>>5) + j*8
    {
        const int cp = tid & 31;          // col-pair
        #pragma unroll
        for (int j = 0; j < 8; ++j) {
            int u = (tid >> 5) + j * 8;
            int t = t0 - 32 + u;
            if (t >= 0) {                 // wave-uniform (chunk==0: skips j<4)
                const void* g = (const void*)(ekn + ((size_t)t * BD + col0 + cp * 2) * 2);
                async_copy16((char*)Et + (tid >> 6) * 1024 + j * 4096, g);
            }
        }
        if (chunk == 0) {                 // zero rows 0..31 (t<0)
            f32x4 z = {0.f, 0.f, 0.f, 0.f};
            #pragma unroll
            for (int j = 0; j < 4; ++j)
                *(f32x4*)((char*)Et + tid * 16 + j * 4096) = z;
        }
    }

    // wl[t_local][j] = valid * exp(pb[t, t-31+j])
    #pragma unroll
    for (int i = 0; i < (CH * SS) / 256; ++i) {
        int idx = tid + i * 256;
        int tl = idx >> 5, jj = idx & 31;
        int t = t0 + tl;
        int u2 = t - (SS - 1) + jj;
        float w = 0.f;
        if (u2 >= 0) w = expf(pb[(size_t)t * TT + u2]);
        wl[tl][jj] = w;
    }

    // qv (sigmoid already applied) + inline chunk-prefix partial
    float qv[8];
    #pragma unroll
    for (int k = 0; k < 8; ++k)
        qv[k] = qf[(size_t)(t0 + s0 + k) * BD + col0 + c];
    f32x2 acc2 = {0.f, 0.f};
    #pragma unroll
    for (int j = 0; j < 16; ++j) {
        int p = sg + 4 * j;
        if (p < chunk)                    // wave-uniform predicate
            acc2 += *(const f32x2*)&part[((size_t)p * BD + col0 + c) * 2];
    }
    *(f32x2*)&red[(sg * 64 + c) * 2] = acc2;

    __syncthreads();                      // drains copies + wl + red

    f32x2 P = *(const f32x2*)&red[(0 * 64 + c) * 2];
    P += *(const f32x2*)&red[(1 * 64 + c) * 2];
    P += *(const f32x2*)&red[(2 * 64 + c) * 2];
    P += *(const f32x2*)&red[(3 * 64 + c) * 2];

    // Pull rows s0+1 .. s0+39 once into registers
    f32x2 ring[39];
    #pragma unroll
    for (int i = 0; i < 39; ++i)
        ring[i] = *(const f32x2*)&Et[((s0 + 1 + i) * 64 + c) * 2];

    // cs(s0) = P - sum_{u=s0+1}^{31} E[u]
    f32x2 cs = P;
    #pragma unroll
    for (int u = 0; u < 31; ++u)
        if (u >= s0) cs -= ring[u - s0];

    #pragma unroll
    for (int k = 0; k < 8; ++k) {
        int s = s0 + k;
        if (k > 0) cs += ring[k - 1];
        f32x2 acc = cs;
        #pragma unroll
        for (int j4 = 0; j4 < 8; ++j4) {
            float4 w4 = *(const float4*)&wl[s][j4 * 4];
            acc += w4.x * ring[k + j4*4 + 0];
            acc += w4.y * ring[k + j4*4 + 1];
            acc += w4.z * ring[k + j4*4 + 2];
            acc += w4.w * ring[k + j4*4 + 3];
        }
        yb[(size_t)(t0 + s) * BD + col0 + c] = __float2bfloat16(qv[k] * acc.y / acc.x);
    }
}

// ---------------------------------------------------------------------------
// out = yb@Wo^T + bo.  yb is bf16 (pass-through stage); Wo fp32 converted
// in-register.  Same 2-buffer reg-staged pipeline as gemm_qkv.
// ---------------------------------------------------------------------------
__global__ __launch_bounds__(256) void gemm_out(
    const __hip_bfloat16* __restrict__ yb, const float* __restrict__ Wo,
    const float* __restrict__ bo, float* __restrict__ out)
{
    __shared__ char smem[16384];
    const int tid = threadIdx.x;
    const int lane = tid & 63;
    const int wv = tid >> 6;
    const int wave_m = wv >> 1, wave_n = wv & 1;
    const int m0 = blockIdx.y * 64, n0 = blockIdx.x * 64;
    const int kq = lane >> 4, rr = lane & 15;
    char* const wr = smem + wv * 1024 + lane * 16;

    const __hip_bfloat16* A = yb + (size_t)(m0 + lane) * DD + wv * 8;
    const float* W = Wo + (size_t)(n0 + lane) * DD + wv * 8;
    f32x4 acc[2][2] = {};
    short8 ra; float4 w0, w1;
#define LDO(t) { ra = *(const short8*)(A + (t)*32); \
                 w0 = *(const float4*)(W + (t)*32); w1 = *(const float4*)(W + (t)*32 + 4); }
#define STO(b) { *(short8*)(wr + (b)*8192) = ra; cvt_store16(wr + (b)*8192 + 4096, w0, w1); }
    LDO(0); STO(0); LDO(1);
    __syncthreads();
    #pragma unroll
    for (int it = 0; it < 16; ++it) {
        const char* cb = smem + (it & 1) * 8192;
        bf16x8 fa0 = *(const bf16x8*)(cb + kq*1024 + (wave_m*32 +  0 + rr)*16);
        bf16x8 fa1 = *(const bf16x8*)(cb + kq*1024 + (wave_m*32 + 16 + rr)*16);
        bf16x8 fw0 = *(const bf16x8*)(cb + 4096 + kq*1024 + (wave_n*32 +  0 + rr)*16);
        bf16x8 fw1 = *(const bf16x8*)(cb + 4096 + kq*1024 + (wave_n*32 + 16 + rr)*16);
        acc[0][0] = MFMA16(fa0, fw0, acc[0][0]);
        acc[0][1] = MFMA16(fa0, fw1, acc[0][1]);
        acc[1][0] = MFMA16(fa1, fw0, acc[1][0]);
        acc[1][1] = MFMA16(fa1, fw1, acc[1][1]);
        if (it + 1 < 16) STO((it + 1) & 1);
        if (it + 2 < 16) LDO(it + 2);
        if (it < 15) __syncthreads();
    }
    #pragma unroll
    for (int ms = 0; ms < 2; ++ms)
        #pragma unroll
        for (int ns = 0; ns < 2; ++ns) {
            int n = n0 + wave_n*32 + ns*16 + rr;
            float bn = bo[n];
            #pragma unroll
            for (int r = 0; r < 4; ++r) {
                int m = m0 + wave_m*32 + ms*16 + kq*4 + r;
                out[(size_t)m * DD + n] = acc[ms][ns][r] + bn;
            }
        }
}

extern "C" void kernel_launch(void* const* d_in, const int* in_sizes, int n_in,
                              void* d_out, int out_size, void* d_ws, size_t ws_size,
                              hipStream_t stream) {
    const float* query = (const float*)d_in[0];
    const float* key   = (const float*)d_in[1];
    const float* value = (const float*)d_in[2];
    const float* Wq    = (const float*)d_in[3];
    const float* bq    = (const float*)d_in[4];
    const float* Wk    = (const float*)d_in[5];
    const float* bk    = (const float*)d_in[6];
    const float* Wv    = (const float*)d_in[7];
    const float* bv    = (const float*)d_in[8];
    const float* pb    = (const float*)d_in[9];
    const float* Wo    = (const float*)d_in[10];
    const float* bo    = (const float*)d_in[11];
    float* out = (float*)d_out;

    float* ws = (float*)d_ws;
    float* qf   = ws;                         // NE (sigmoid(q))
    float* ekn  = ws + (size_t)NE;            // 2*NE (interleaved {den,num})
    float* part = ws + (size_t)3 * NE;        // 2*64*1024 = 131072
    __hip_bfloat16* yb = (__hip_bfloat16*)(part + 131072);  // NE bf16

    gemm_qkv<<<dim3(DD / 64, MR / 64, 2), 256, 0, stream>>>(
        query, key, value, Wq, Wk, Wv, bq, bk, bv,
        qf, ekn, part);

    fused_window<<<dim3(BD / 64, TT / CH), 256, 0, stream>>>(
        qf, ekn, part, pb, yb);

    gemm_out<<<dim3(DD / 64, MR / 64), 256, 0, stream>>>(yb, Wo, bo, out);
}

// Round 7
// 187.488 us; speedup vs baseline: 2.5214x; 1.1571x over previous
//
#include <hip/hip_runtime.h>
#include <hip/hip_bf16.h>

// Problem constants (AFTLocalAutoregressive): T=2048, B=2, D=512, S=32
#define TT 2048
#define BB 2
#define DD 512
#define BD (BB*DD)        // 1024 columns (b,d flattened)
#define SS 32
#define MR (TT*BB)        // 4096 GEMM rows; m = 2t + b
#define NE (TT*BB*DD)     // 2097152 elements per (T,B,D) tensor
#define CH 32             // t-chunk size for scan/window (== one 64-row m-tile)

typedef __bf16 bf16x8 __attribute__((ext_vector_type(8)));
typedef float f32x4 __attribute__((ext_vector_type(4)));
typedef float f32x2 __attribute__((ext_vector_type(2)));

__device__ __forceinline__ void async_copy16(void* lds, const void* gptr) {
    __builtin_amdgcn_global_load_lds(
        (const __attribute__((address_space(1))) void*)gptr,
        (__attribute__((address_space(3))) void*)lds,
        16, 0, 0);
}

#define MFMA16(a,b,c) __builtin_amdgcn_mfma_f32_16x16x32_bf16((a),(b),(c),0,0,0)

// fp32 -> bf16: blocks 0..6143 cover query/key/value; 6144..7167 cover 4 weights
__global__ __launch_bounds__(256) void cast_all(
    const float* __restrict__ s0, const float* __restrict__ s1, const float* __restrict__ s2,
    const float* __restrict__ w0, const float* __restrict__ w1,
    const float* __restrict__ w2, const float* __restrict__ w3,
    __hip_bfloat16* __restrict__ d0, __hip_bfloat16* __restrict__ d1, __hip_bfloat16* __restrict__ d2,
    __hip_bfloat16* __restrict__ e0, __hip_bfloat16* __restrict__ e1,
    __hip_bfloat16* __restrict__ e2, __hip_bfloat16* __restrict__ e3)
{
    int b = blockIdx.x;
    const float* s;
    __hip_bfloat16* d;
    size_t i;
    if (b < 6144) {
        int which = b >> 11;
        s = which == 0 ? s0 : (which == 1 ? s1 : s2);
        d = which == 0 ? d0 : (which == 1 ? d1 : d2);
        i = ((size_t)(b & 2047) * 256 + threadIdx.x) * 4;
    } else {
        int b2 = b - 6144;
        int which = b2 >> 8;
        s = which == 0 ? w0 : (which == 1 ? w1 : (which == 2 ? w2 : w3));
        d = which == 0 ? e0 : (which == 1 ? e1 : (which == 2 ? e2 : e3));
        i = ((size_t)(b2 & 255) * 256 + threadIdx.x) * 4;
    }
    float4 f = *(const float4*)(s + i);
    union { __hip_bfloat16 h[4]; ushort4 u; } cv;
    cv.h[0] = __float2bfloat16(f.x); cv.h[1] = __float2bfloat16(f.y);
    cv.h[2] = __float2bfloat16(f.z); cv.h[3] = __float2bfloat16(f.w);
    *(ushort4*)((unsigned short*)d + i) = cv.u;
}

// ---------------------------------------------------------------------------
// z=0: qf = sigmoid(query@Wq^T + bq)  (fp32 out; sigmoid folded in)
// z=1: k,v projections fused; epilogue writes interleaved ekn = {ek, ek*v}
//      AND per-chunk column sums part.
// All operands bf16 via global_load_lds, 3-deep staged pipeline: stage tile
// it+2, compute tile it, counted s_waitcnt vmcnt + raw s_barrier per iter
// (never full drain mid-loop).  Verified structure from round 1 (passed).
// ---------------------------------------------------------------------------
__global__ __launch_bounds__(256) void gemm_qkv(
    const __hip_bfloat16* __restrict__ qb, const __hip_bfloat16* __restrict__ kb,
    const __hip_bfloat16* __restrict__ vb,
    const __hip_bfloat16* __restrict__ Wqb, const __hip_bfloat16* __restrict__ Wkb,
    const __hip_bfloat16* __restrict__ Wvb,
    const float* __restrict__ bq, const float* __restrict__ bk,
    const float* __restrict__ bv,
    float* __restrict__ qout, float* __restrict__ ekn,
    float* __restrict__ part)
{
    __shared__ char smem[49152];          // 3 buffers (z=1: 16KB each, z=0: 8KB)
    const int tid = threadIdx.x;
    const int lane = tid & 63;
    const int wv = tid >> 6;
    const int wave_m = wv >> 1, wave_n = wv & 1;
    const int m0 = blockIdx.y * 64, n0 = blockIdx.x * 64;
    const int kq = lane >> 4, rr = lane & 15;

    if (blockIdx.z == 0) {
        f32x4 acc[2][2] = {};
        const __hip_bfloat16* Arow = qb + (size_t)(m0 + lane) * DD + wv * 8;
        const __hip_bfloat16* Wrow = Wqb + (size_t)(n0 + lane) * DD + wv * 8;
        async_copy16(smem + 0*8192 +        wv*1024, Arow + 0);
        async_copy16(smem + 0*8192 + 4096 + wv*1024, Wrow + 0);
        async_copy16(smem + 1*8192 +        wv*1024, Arow + 32);
        async_copy16(smem + 1*8192 + 4096 + wv*1024, Wrow + 32);
        asm volatile("s_waitcnt vmcnt(2)" ::: "memory");   // tile 0 landed
        __builtin_amdgcn_s_barrier();
        #pragma unroll
        for (int it = 0; it < 16; ++it) {
            if (it + 2 < 16) {
                char* nb = smem + ((it + 2) % 3) * 8192;
                async_copy16(nb +        wv*1024, Arow + (it+2)*32);
                async_copy16(nb + 4096 + wv*1024, Wrow + (it+2)*32);
            }
            const char* cb = smem + (it % 3) * 8192;
            bf16x8 a0 = *(const bf16x8*)(cb + kq*1024 + (wave_m*32 +  0 + rr)*16);
            bf16x8 a1 = *(const bf16x8*)(cb + kq*1024 + (wave_m*32 + 16 + rr)*16);
            bf16x8 w0 = *(const bf16x8*)(cb + 4096 + kq*1024 + (wave_n*32 +  0 + rr)*16);
            bf16x8 w1 = *(const bf16x8*)(cb + 4096 + kq*1024 + (wave_n*32 + 16 + rr)*16);
            acc[0][0] = MFMA16(a0, w0, acc[0][0]);
            acc[0][1] = MFMA16(a0, w1, acc[0][1]);
            acc[1][0] = MFMA16(a1, w0, acc[1][0]);
            acc[1][1] = MFMA16(a1, w1, acc[1][1]);
            if (it < 15) {
                if (it < 14) asm volatile("s_waitcnt vmcnt(2) lgkmcnt(0)" ::: "memory");
                else         asm volatile("s_waitcnt vmcnt(0) lgkmcnt(0)" ::: "memory");
                __builtin_amdgcn_s_barrier();
            }
        }
        #pragma unroll
        for (int ms = 0; ms < 2; ++ms)
            #pragma unroll
            for (int ns = 0; ns < 2; ++ns) {
                int n = n0 + wave_n*32 + ns*16 + rr;
                float bn = bq[n];
                #pragma unroll
                for (int r = 0; r < 4; ++r) {
                    int m = m0 + wave_m*32 + ms*16 + kq*4 + r;
                    float x = acc[ms][ns][r] + bn;
                    qout[(size_t)m * DD + n] = 1.f / (1.f + expf(-x));  // sigmoid folded
                }
            }
    } else {
        f32x4 acck[2][2] = {}, accv[2][2] = {};
        const __hip_bfloat16* AKrow = kb + (size_t)(m0 + lane) * DD + wv * 8;
        const __hip_bfloat16* WKrow = Wkb + (size_t)(n0 + lane) * DD + wv * 8;
        const __hip_bfloat16* AVrow = vb + (size_t)(m0 + lane) * DD + wv * 8;
        const __hip_bfloat16* WVrow = Wvb + (size_t)(n0 + lane) * DD + wv * 8;
        #pragma unroll
        for (int pt = 0; pt < 2; ++pt) {
            char* nb = smem + pt * 16384;
            async_copy16(nb +         wv*1024, AKrow + pt*32);
            async_copy16(nb +  4096 + wv*1024, WKrow + pt*32);
            async_copy16(nb +  8192 + wv*1024, AVrow + pt*32);
            async_copy16(nb + 12288 + wv*1024, WVrow + pt*32);
        }
        asm volatile("s_waitcnt vmcnt(4)" ::: "memory");   // tile 0 landed
        __builtin_amdgcn_s_barrier();
        #pragma unroll
        for (int it = 0; it < 16; ++it) {
            if (it + 2 < 16) {
                char* nb = smem + ((it + 2) % 3) * 16384;
                async_copy16(nb +         wv*1024, AKrow + (it+2)*32);
                async_copy16(nb +  4096 + wv*1024, WKrow + (it+2)*32);
                async_copy16(nb +  8192 + wv*1024, AVrow + (it+2)*32);
                async_copy16(nb + 12288 + wv*1024, WVrow + (it+2)*32);
            }
            const char* cb = smem + (it % 3) * 16384;
            bf16x8 ak0 = *(const bf16x8*)(cb +         kq*1024 + (wave_m*32 +  0 + rr)*16);
            bf16x8 ak1 = *(const bf16x8*)(cb +         kq*1024 + (wave_m*32 + 16 + rr)*16);
            bf16x8 bk0 = *(const bf16x8*)(cb +  4096 + kq*1024 + (wave_n*32 +  0 + rr)*16);
            bf16x8 bk1 = *(const bf16x8*)(cb +  4096 + kq*1024 + (wave_n*32 + 16 + rr)*16);
            bf16x8 av0 = *(const bf16x8*)(cb +  8192 + kq*1024 + (wave_m*32 +  0 + rr)*16);
            bf16x8 av1 = *(const bf16x8*)(cb +  8192 + kq*1024 + (wave_m*32 + 16 + rr)*16);
            bf16x8 bv0 = *(const bf16x8*)(cb + 12288 + kq*1024 + (wave_n*32 +  0 + rr)*16);
            bf16x8 bv1 = *(const bf16x8*)(cb + 12288 + kq*1024 + (wave_n*32 + 16 + rr)*16);
            acck[0][0] = MFMA16(ak0, bk0, acck[0][0]);
            acck[0][1] = MFMA16(ak0, bk1, acck[0][1]);
            acck[1][0] = MFMA16(ak1, bk0, acck[1][0]);
            acck[1][1] = MFMA16(ak1, bk1, acck[1][1]);
            accv[0][0] = MFMA16(av0, bv0, accv[0][0]);
            accv[0][1] = MFMA16(av0, bv1, accv[0][1]);
            accv[1][0] = MFMA16(av1, bv0, accv[1][0]);
            accv[1][1] = MFMA16(av1, bv1, accv[1][1]);
            if (it < 15) {
                if (it < 14) asm volatile("s_waitcnt vmcnt(4) lgkmcnt(0)" ::: "memory");
                else         asm volatile("s_waitcnt vmcnt(0) lgkmcnt(0)" ::: "memory");
                __builtin_amdgcn_s_barrier();
            }
        }
        // epilogue: interleaved ekn stores + per-chunk column sums (b = r&1)
        float sd[2][2] = {{0.f,0.f},{0.f,0.f}};   // [ns][parity]
        float sn[2][2] = {{0.f,0.f},{0.f,0.f}};
        #pragma unroll
        for (int ms = 0; ms < 2; ++ms)
            #pragma unroll
            for (int ns = 0; ns < 2; ++ns) {
                int n = n0 + wave_n*32 + ns*16 + rr;
                float bkn = bk[n], bvn = bv[n];
                #pragma unroll
                for (int r = 0; r < 4; ++r) {
                    int m = m0 + wave_m*32 + ms*16 + kq*4 + r;
                    float e  = expf(acck[ms][ns][r] + bkn);
                    float nv = e * (accv[ms][ns][r] + bvn);
                    float2 st; st.x = e; st.y = nv;
                    *(float2*)&ekn[((size_t)m * DD + n) * 2] = st;
                    sd[ns][r & 1] += e;
                    sn[ns][r & 1] += nv;
                }
            }
        #pragma unroll
        for (int ns = 0; ns < 2; ++ns)
            #pragma unroll
            for (int par = 0; par < 2; ++par) {
                sd[ns][par] += __shfl_xor(sd[ns][par], 16, 64);
                sd[ns][par] += __shfl_xor(sd[ns][par], 32, 64);
                sn[ns][par] += __shfl_xor(sn[ns][par], 16, 64);
                sn[ns][par] += __shfl_xor(sn[ns][par], 32, 64);
            }
        __syncthreads();                       // smem free for reuse
        float* red = (float*)smem;             // red[which(4)][wave_m(2)][64]
        if (lane < 16) {
            #pragma unroll
            for (int ns = 0; ns < 2; ++ns) {
                int c2 = wave_n*32 + ns*16 + rr;
                red[(0*2 + wave_m)*64 + c2] = sd[ns][0];
                red[(1*2 + wave_m)*64 + c2] = sd[ns][1];
                red[(2*2 + wave_m)*64 + c2] = sn[ns][0];
                red[(3*2 + wave_m)*64 + c2] = sn[ns][1];
            }
        }
        __syncthreads();
        {
            int which = tid >> 6;              // 0: d,b0  1: d,b1  2: n,b0  3: n,b1
            int c2 = tid & 63;
            float s = red[(which*2 + 0)*64 + c2] + red[(which*2 + 1)*64 + c2];
            int b = which & 1;
            int sel = which >> 1;              // 0 = den, 1 = num
            part[((size_t)blockIdx.y * BD + b*512 + n0 + c2) * 2 + sel] = s;
        }
    }
}

// ---------------------------------------------------------------------------
// fused_window: LDS-staged E-tile + inline chunk-prefix reduction + register
// window ring.  Grid (BD/64, T/CH) = (16, 64) = 1024 blocks, 4 blocks/CU.
// Verified structure from rounds 3/5/6 (passed).  qf holds sigmoid(q).
// ---------------------------------------------------------------------------
__global__ __launch_bounds__(256, 3) void fused_window(
    const float* __restrict__ qf, const float* __restrict__ ekn,
    const float* __restrict__ part, const float* __restrict__ pb,
    __hip_bfloat16* __restrict__ yb)
{
    __shared__ float Et[64 * 64 * 2];     // 32 KB: [u][c] f32x2
    __shared__ float wl[CH][SS];          // 4 KB
    __shared__ float red[4 * 64 * 2];     // 2 KB
    const int tid = threadIdx.x;
    const int chunk = blockIdx.y;
    const int t0 = chunk * CH;
    const int col0 = blockIdx.x * 64;
    const int c = tid & 63;
    const int sg = tid >> 6;              // wave = s-group
    const int s0 = sg * 8;

    // Stage E tile: thread covers 16B (2 cols) of row u = (tid>>5) + j*8
    {
        const int cp = tid & 31;          // col-pair
        #pragma unroll
        for (int j = 0; j < 8; ++j) {
            int u = (tid >> 5) + j * 8;
            int t = t0 - 32 + u;
            if (t >= 0) {                 // wave-uniform (chunk==0: skips j<4)
                const void* g = (const void*)(ekn + ((size_t)t * BD + col0 + cp * 2) * 2);
                async_copy16((char*)Et + (tid >> 6) * 1024 + j * 4096, g);
            }
        }
        if (chunk == 0) {                 // zero rows 0..31 (t<0)
            f32x4 z = {0.f, 0.f, 0.f, 0.f};
            #pragma unroll
            for (int j = 0; j < 4; ++j)
                *(f32x4*)((char*)Et + tid * 16 + j * 4096) = z;
        }
    }

    // wl[t_local][j] = valid * exp(pb[t, t-31+j])
    #pragma unroll
    for (int i = 0; i < (CH * SS) / 256; ++i) {
        int idx = tid + i * 256;
        int tl = idx >> 5, jj = idx & 31;
        int t = t0 + tl;
        int u2 = t - (SS - 1) + jj;
        float w = 0.f;
        if (u2 >= 0) w = expf(pb[(size_t)t * TT + u2]);
        wl[tl][jj] = w;
    }

    // qv (sigmoid already applied) + inline chunk-prefix partial
    float qv[8];
    #pragma unroll
    for (int k = 0; k < 8; ++k)
        qv[k] = qf[(size_t)(t0 + s0 + k) * BD + col0 + c];
    f32x2 acc2 = {0.f, 0.f};
    #pragma unroll
    for (int j = 0; j < 16; ++j) {
        int p = sg + 4 * j;
        if (p < chunk)                    // wave-uniform predicate
            acc2 += *(const f32x2*)&part[((size_t)p * BD + col0 + c) * 2];
    }
    *(f32x2*)&red[(sg * 64 + c) * 2] = acc2;

    __syncthreads();                      // drains copies + wl + red

    f32x2 P = *(const f32x2*)&red[(0 * 64 + c) * 2];
    P += *(const f32x2*)&red[(1 * 64 + c) * 2];
    P += *(const f32x2*)&red[(2 * 64 + c) * 2];
    P += *(const f32x2*)&red[(3 * 64 + c) * 2];

    // Pull rows s0+1 .. s0+39 once into registers
    f32x2 ring[39];
    #pragma unroll
    for (int i = 0; i < 39; ++i)
        ring[i] = *(const f32x2*)&Et[((s0 + 1 + i) * 64 + c) * 2];

    // cs(s0) = P - sum_{u=s0+1}^{31} E[u]
    f32x2 cs = P;
    #pragma unroll
    for (int u = 0; u < 31; ++u)
        if (u >= s0) cs -= ring[u - s0];

    #pragma unroll
    for (int k = 0; k < 8; ++k) {
        int s = s0 + k;
        if (k > 0) cs += ring[k - 1];
        f32x2 acc = cs;
        #pragma unroll
        for (int j4 = 0; j4 < 8; ++j4) {
            float4 w4 = *(const float4*)&wl[s][j4 * 4];
            acc += w4.x * ring[k + j4*4 + 0];
            acc += w4.y * ring[k + j4*4 + 1];
            acc += w4.z * ring[k + j4*4 + 2];
            acc += w4.w * ring[k + j4*4 + 3];
        }
        yb[(size_t)(t0 + s) * BD + col0 + c] = __float2bfloat16(qv[k] * acc.y / acc.x);
    }
}

// out = yb@Wo^T + bo.  Both operands bf16, 3-deep global_load_lds pipeline
// (verified structure from round 1).
__global__ __launch_bounds__(256) void gemm_out(
    const __hip_bfloat16* __restrict__ yb, const __hip_bfloat16* __restrict__ Wob,
    const float* __restrict__ bo, float* __restrict__ out)
{
    __shared__ char smem[24576];          // 3 buffers of 8KB
    const int tid = threadIdx.x;
    const int lane = tid & 63;
    const int wv = tid >> 6;
    const int wave_m = wv >> 1, wave_n = wv & 1;
    const int m0 = blockIdx.y * 64, n0 = blockIdx.x * 64;
    const int kq = lane >> 4, rr = lane & 15;

    f32x4 acc[2][2] = {};
    const __hip_bfloat16* Arow = yb + (size_t)(m0 + lane) * DD + wv * 8;
    const __hip_bfloat16* Wrow = Wob + (size_t)(n0 + lane) * DD + wv * 8;

    async_copy16(smem + 0*8192 +        wv*1024, Arow + 0);
    async_copy16(smem + 0*8192 + 4096 + wv*1024, Wrow + 0);
    async_copy16(smem + 1*8192 +        wv*1024, Arow + 32);
    async_copy16(smem + 1*8192 + 4096 + wv*1024, Wrow + 32);
    asm volatile("s_waitcnt vmcnt(2)" ::: "memory");
    __builtin_amdgcn_s_barrier();
    #pragma unroll
    for (int it = 0; it < 16; ++it) {
        if (it + 2 < 16) {
            char* nb = smem + ((it + 2) % 3) * 8192;
            async_copy16(nb +        wv*1024, Arow + (it+2)*32);
            async_copy16(nb + 4096 + wv*1024, Wrow + (it+2)*32);
        }
        const char* cb = smem + (it % 3) * 8192;
        bf16x8 a0 = *(const bf16x8*)(cb + kq*1024 + (wave_m*32 +  0 + rr)*16);
        bf16x8 a1 = *(const bf16x8*)(cb + kq*1024 + (wave_m*32 + 16 + rr)*16);
        bf16x8 w0 = *(const bf16x8*)(cb + 4096 + kq*1024 + (wave_n*32 +  0 + rr)*16);
        bf16x8 w1 = *(const bf16x8*)(cb + 4096 + kq*1024 + (wave_n*32 + 16 + rr)*16);
        acc[0][0] = MFMA16(a0, w0, acc[0][0]);
        acc[0][1] = MFMA16(a0, w1, acc[0][1]);
        acc[1][0] = MFMA16(a1, w0, acc[1][0]);
        acc[1][1] = MFMA16(a1, w1, acc[1][1]);
        if (it < 15) {
            if (it < 14) asm volatile("s_waitcnt vmcnt(2) lgkmcnt(0)" ::: "memory");
            else         asm volatile("s_waitcnt vmcnt(0) lgkmcnt(0)" ::: "memory");
            __builtin_amdgcn_s_barrier();
        }
    }
    #pragma unroll
    for (int ms = 0; ms < 2; ++ms)
        #pragma unroll
        for (int ns = 0; ns < 2; ++ns) {
            int n = n0 + wave_n*32 + ns*16 + rr;
            float bn = bo[n];
            #pragma unroll
            for (int r = 0; r < 4; ++r) {
                int m = m0 + wave_m*32 + ms*16 + kq*4 + r;
                out[(size_t)m * DD + n] = acc[ms][ns][r] + bn;
            }
        }
}

extern "C" void kernel_launch(void* const* d_in, const int* in_sizes, int n_in,
                              void* d_out, int out_size, void* d_ws, size_t ws_size,
                              hipStream_t stream) {
    const float* query = (const float*)d_in[0];
    const float* key   = (const float*)d_in[1];
    const float* value = (const float*)d_in[2];
    const float* Wq    = (const float*)d_in[3];
    const float* bq    = (const float*)d_in[4];
    const float* Wk    = (const float*)d_in[5];
    const float* bk    = (const float*)d_in[6];
    const float* Wv    = (const float*)d_in[7];
    const float* bv    = (const float*)d_in[8];
    const float* pb    = (const float*)d_in[9];
    const float* Wo    = (const float*)d_in[10];
    const float* bo    = (const float*)d_in[11];
    float* out = (float*)d_out;

    float* ws = (float*)d_ws;
    float* qf   = ws;                         // NE (sigmoid(q))
    float* ekn  = ws + (size_t)NE;            // 2*NE (interleaved {den,num})
    float* part = ws + (size_t)3 * NE;        // 2*64*1024 = 131072
    __hip_bfloat16* bfb = (__hip_bfloat16*)(part + 131072);
    __hip_bfloat16* qb  = bfb;                // NE each
    __hip_bfloat16* kb  = bfb + (size_t)NE;
    __hip_bfloat16* vb  = bfb + (size_t)2 * NE;
    __hip_bfloat16* yb  = bfb + (size_t)3 * NE;
    __hip_bfloat16* Wqb = bfb + (size_t)4 * NE;   // 262144 each
    __hip_bfloat16* Wkb = Wqb + 262144;
    __hip_bfloat16* Wvb = Wkb + 262144;
    __hip_bfloat16* Wob = Wvb + 262144;

    cast_all<<<7168, 256, 0, stream>>>(query, key, value, Wq, Wk, Wv, Wo,
                                       qb, kb, vb, Wqb, Wkb, Wvb, Wob);

    gemm_qkv<<<dim3(DD / 64, MR / 64, 2), 256, 0, stream>>>(
        qb, kb, vb, Wqb, Wkb, Wvb, bq, bk, bv,
        qf, ekn, part);

    fused_window<<<dim3(BD / 64, TT / CH), 256, 0, stream>>>(
        qf, ekn, part, pb, yb);

    gemm_out<<<dim3(DD / 64, MR / 64), 256, 0, stream>>>(yb, Wob, bo, out);
}

// Round 8
// 155.543 us; speedup vs baseline: 3.0392x; 1.2054x over previous
//
#include <hip/hip_runtime.h>
#include <hip/hip_bf16.h>

// Problem constants (AFTLocalAutoregressive): T=2048, B=2, D=512, S=32
#define TT 2048
#define BB 2
#define DD 512
#define BD (BB*DD)        // 1024 columns (b,d flattened)
#define SS 32
#define MR (TT*BB)        // 4096 GEMM rows; m = 2t + b
#define NE (TT*BB*DD)     // 2097152 elements per (T,B,D) tensor
#define CH 32             // t-chunk size for scan/window (== one 64-row m-tile)

typedef __bf16 bf16x8 __attribute__((ext_vector_type(8)));
typedef float f32x4 __attribute__((ext_vector_type(4)));
typedef float f32x2 __attribute__((ext_vector_type(2)));

__device__ __forceinline__ void async_copy16(void* lds, const void* gptr) {
    __builtin_amdgcn_global_load_lds(
        (const __attribute__((address_space(1))) void*)gptr,
        (__attribute__((address_space(3))) void*)lds,
        16, 0, 0);
}

#define MFMA16(a,b,c) __builtin_amdgcn_mfma_f32_16x16x32_bf16((a),(b),(c),0,0,0)

// fp32 -> bf16: blocks 0..6143 cover query/key/value; 6144..7167 cover 4 weights
__global__ __launch_bounds__(256) void cast_all(
    const float* __restrict__ s0, const float* __restrict__ s1, const float* __restrict__ s2,
    const float* __restrict__ w0, const float* __restrict__ w1,
    const float* __restrict__ w2, const float* __restrict__ w3,
    __hip_bfloat16* __restrict__ d0, __hip_bfloat16* __restrict__ d1, __hip_bfloat16* __restrict__ d2,
    __hip_bfloat16* __restrict__ e0, __hip_bfloat16* __restrict__ e1,
    __hip_bfloat16* __restrict__ e2, __hip_bfloat16* __restrict__ e3)
{
    int b = blockIdx.x;
    const float* s;
    __hip_bfloat16* d;
    size_t i;
    if (b < 6144) {
        int which = b >> 11;
        s = which == 0 ? s0 : (which == 1 ? s1 : s2);
        d = which == 0 ? d0 : (which == 1 ? d1 : d2);
        i = ((size_t)(b & 2047) * 256 + threadIdx.x) * 4;
    } else {
        int b2 = b - 6144;
        int which = b2 >> 8;
        s = which == 0 ? w0 : (which == 1 ? w1 : (which == 2 ? w2 : w3));
        d = which == 0 ? e0 : (which == 1 ? e1 : (which == 2 ? e2 : e3));
        i = ((size_t)(b2 & 255) * 256 + threadIdx.x) * 4;
    }
    float4 f = *(const float4*)(s + i);
    union { __hip_bfloat16 h[4]; ushort4 u; } cv;
    cv.h[0] = __float2bfloat16(f.x); cv.h[1] = __float2bfloat16(f.y);
    cv.h[2] = __float2bfloat16(f.z); cv.h[3] = __float2bfloat16(f.w);
    *(ushort4*)((unsigned short*)d + i) = cv.u;
}

// ---------------------------------------------------------------------------
// z=0: qf = sigmoid(query@Wq^T + bq)  (fp32 out; sigmoid folded in)
// z=1: k,v projections fused; epilogue writes interleaved ekn = {ek, ek*v}
//      AND per-chunk column sums part.
// All operands bf16 via global_load_lds, 3-deep staged pipeline: stage tile
// it+2, compute tile it, counted s_waitcnt vmcnt + raw s_barrier per iter
// (never full drain mid-loop).  Verified structure from round 1 (passed).
// ---------------------------------------------------------------------------
__global__ __launch_bounds__(256) void gemm_qkv(
    const __hip_bfloat16* __restrict__ qb, const __hip_bfloat16* __restrict__ kb,
    const __hip_bfloat16* __restrict__ vb,
    const __hip_bfloat16* __restrict__ Wqb, const __hip_bfloat16* __restrict__ Wkb,
    const __hip_bfloat16* __restrict__ Wvb,
    const float* __restrict__ bq, const float* __restrict__ bk,
    const float* __restrict__ bv,
    float* __restrict__ qout, float* __restrict__ ekn,
    float* __restrict__ part)
{
    __shared__ char smem[49152];          // 3 buffers (z=1: 16KB each, z=0: 8KB)
    const int tid = threadIdx.x;
    const int lane = tid & 63;
    const int wv = tid >> 6;
    const int wave_m = wv >> 1, wave_n = wv & 1;
    const int m0 = blockIdx.y * 64, n0 = blockIdx.x * 64;
    const int kq = lane >> 4, rr = lane & 15;

    if (blockIdx.z == 0) {
        f32x4 acc[2][2] = {};
        const __hip_bfloat16* Arow = qb + (size_t)(m0 + lane) * DD + wv * 8;
        const __hip_bfloat16* Wrow = Wqb + (size_t)(n0 + lane) * DD + wv * 8;
        async_copy16(smem + 0*8192 +        wv*1024, Arow + 0);
        async_copy16(smem + 0*8192 + 4096 + wv*1024, Wrow + 0);
        async_copy16(smem + 1*8192 +        wv*1024, Arow + 32);
        async_copy16(smem + 1*8192 + 4096 + wv*1024, Wrow + 32);
        asm volatile("s_waitcnt vmcnt(2)" ::: "memory");   // tile 0 landed
        __builtin_amdgcn_s_barrier();
        #pragma unroll
        for (int it = 0; it < 16; ++it) {
            if (it + 2 < 16) {
                char* nb = smem + ((it + 2) % 3) * 8192;
                async_copy16(nb +        wv*1024, Arow + (it+2)*32);
                async_copy16(nb + 4096 + wv*1024, Wrow + (it+2)*32);
            }
            const char* cb = smem + (it % 3) * 8192;
            bf16x8 a0 = *(const bf16x8*)(cb + kq*1024 + (wave_m*32 +  0 + rr)*16);
            bf16x8 a1 = *(const bf16x8*)(cb + kq*1024 + (wave_m*32 + 16 + rr)*16);
            bf16x8 w0 = *(const bf16x8*)(cb + 4096 + kq*1024 + (wave_n*32 +  0 + rr)*16);
            bf16x8 w1 = *(const bf16x8*)(cb + 4096 + kq*1024 + (wave_n*32 + 16 + rr)*16);
            acc[0][0] = MFMA16(a0, w0, acc[0][0]);
            acc[0][1] = MFMA16(a0, w1, acc[0][1]);
            acc[1][0] = MFMA16(a1, w0, acc[1][0]);
            acc[1][1] = MFMA16(a1, w1, acc[1][1]);
            if (it < 15) {
                if (it < 14) asm volatile("s_waitcnt vmcnt(2) lgkmcnt(0)" ::: "memory");
                else         asm volatile("s_waitcnt vmcnt(0) lgkmcnt(0)" ::: "memory");
                __builtin_amdgcn_s_barrier();
            }
        }
        #pragma unroll
        for (int ms = 0; ms < 2; ++ms)
            #pragma unroll
            for (int ns = 0; ns < 2; ++ns) {
                int n = n0 + wave_n*32 + ns*16 + rr;
                float bn = bq[n];
                #pragma unroll
                for (int r = 0; r < 4; ++r) {
                    int m = m0 + wave_m*32 + ms*16 + kq*4 + r;
                    float x = acc[ms][ns][r] + bn;
                    qout[(size_t)m * DD + n] = 1.f / (1.f + expf(-x));  // sigmoid folded
                }
            }
    } else {
        f32x4 acck[2][2] = {}, accv[2][2] = {};
        const __hip_bfloat16* AKrow = kb + (size_t)(m0 + lane) * DD + wv * 8;
        const __hip_bfloat16* WKrow = Wkb + (size_t)(n0 + lane) * DD + wv * 8;
        const __hip_bfloat16* AVrow = vb + (size_t)(m0 + lane) * DD + wv * 8;
        const __hip_bfloat16* WVrow = Wvb + (size_t)(n0 + lane) * DD + wv * 8;
        #pragma unroll
        for (int pt = 0; pt < 2; ++pt) {
            char* nb = smem + pt * 16384;
            async_copy16(nb +         wv*1024, AKrow + pt*32);
            async_copy16(nb +  4096 + wv*1024, WKrow + pt*32);
            async_copy16(nb +  8192 + wv*1024, AVrow + pt*32);
            async_copy16(nb + 12288 + wv*1024, WVrow + pt*32);
        }
        asm volatile("s_waitcnt vmcnt(4)" ::: "memory");   // tile 0 landed
        __builtin_amdgcn_s_barrier();
        #pragma unroll
        for (int it = 0; it < 16; ++it) {
            if (it + 2 < 16) {
                char* nb = smem + ((it + 2) % 3) * 16384;
                async_copy16(nb +         wv*1024, AKrow + (it+2)*32);
                async_copy16(nb +  4096 + wv*1024, WKrow + (it+2)*32);
                async_copy16(nb +  8192 + wv*1024, AVrow + (it+2)*32);
                async_copy16(nb + 12288 + wv*1024, WVrow + (it+2)*32);
            }
            const char* cb = smem + (it % 3) * 16384;
            bf16x8 ak0 = *(const bf16x8*)(cb +         kq*1024 + (wave_m*32 +  0 + rr)*16);
            bf16x8 ak1 = *(const bf16x8*)(cb +         kq*1024 + (wave_m*32 + 16 + rr)*16);
            bf16x8 bk0 = *(const bf16x8*)(cb +  4096 + kq*1024 + (wave_n*32 +  0 + rr)*16);
            bf16x8 bk1 = *(const bf16x8*)(cb +  4096 + kq*1024 + (wave_n*32 + 16 + rr)*16);
            bf16x8 av0 = *(const bf16x8*)(cb +  8192 + kq*1024 + (wave_m*32 +  0 + rr)*16);
            bf16x8 av1 = *(const bf16x8*)(cb +  8192 + kq*1024 + (wave_m*32 + 16 + rr)*16);
            bf16x8 bv0 = *(const bf16x8*)(cb + 12288 + kq*1024 + (wave_n*32 +  0 + rr)*16);
            bf16x8 bv1 = *(const bf16x8*)(cb + 12288 + kq*1024 + (wave_n*32 + 16 + rr)*16);
            acck[0][0] = MFMA16(ak0, bk0, acck[0][0]);
            acck[0][1] = MFMA16(ak0, bk1, acck[0][1]);
            acck[1][0] = MFMA16(ak1, bk0, acck[1][0]);
            acck[1][1] = MFMA16(ak1, bk1, acck[1][1]);
            accv[0][0] = MFMA16(av0, bv0, accv[0][0]);
            accv[0][1] = MFMA16(av0, bv1, accv[0][1]);
            accv[1][0] = MFMA16(av1, bv0, accv[1][0]);
            accv[1][1] = MFMA16(av1, bv1, accv[1][1]);
            if (it < 15) {
                if (it < 14) asm volatile("s_waitcnt vmcnt(4) lgkmcnt(0)" ::: "memory");
                else         asm volatile("s_waitcnt vmcnt(0) lgkmcnt(0)" ::: "memory");
                __builtin_amdgcn_s_barrier();
            }
        }
        // epilogue: interleaved ekn stores + per-chunk column sums (b = r&1)
        float sd[2][2] = {{0.f,0.f},{0.f,0.f}};   // [ns][parity]
        float sn[2][2] = {{0.f,0.f},{0.f,0.f}};
        #pragma unroll
        for (int ms = 0; ms < 2; ++ms)
            #pragma unroll
            for (int ns = 0; ns < 2; ++ns) {
                int n = n0 + wave_n*32 + ns*16 + rr;
                float bkn = bk[n], bvn = bv[n];
                #pragma unroll
                for (int r = 0; r < 4; ++r) {
                    int m = m0 + wave_m*32 + ms*16 + kq*4 + r;
                    float e  = expf(acck[ms][ns][r] + bkn);
                    float nv = e * (accv[ms][ns][r] + bvn);
                    float2 st; st.x = e; st.y = nv;
                    *(float2*)&ekn[((size_t)m * DD + n) * 2] = st;
                    sd[ns][r & 1] += e;
                    sn[ns][r & 1] += nv;
                }
            }
        #pragma unroll
        for (int ns = 0; ns < 2; ++ns)
            #pragma unroll
            for (int par = 0; par < 2; ++par) {
                sd[ns][par] += __shfl_xor(sd[ns][par], 16, 64);
                sd[ns][par] += __shfl_xor(sd[ns][par], 32, 64);
                sn[ns][par] += __shfl_xor(sn[ns][par], 16, 64);
                sn[ns][par] += __shfl_xor(sn[ns][par], 32, 64);
            }
        __syncthreads();                       // smem free for reuse
        float* red = (float*)smem;             // red[which(4)][wave_m(2)][64]
        if (lane < 16) {
            #pragma unroll
            for (int ns = 0; ns < 2; ++ns) {
                int c2 = wave_n*32 + ns*16 + rr;
                red[(0*2 + wave_m)*64 + c2] = sd[ns][0];
                red[(1*2 + wave_m)*64 + c2] = sd[ns][1];
                red[(2*2 + wave_m)*64 + c2] = sn[ns][0];
                red[(3*2 + wave_m)*64 + c2] = sn[ns][1];
            }
        }
        __syncthreads();
        {
            int which = tid >> 6;              // 0: d,b0  1: d,b1  2: n,b0  3: n,b1
            int c2 = tid & 63;
            float s = red[(which*2 + 0)*64 + c2] + red[(which*2 + 1)*64 + c2];
            int b = which & 1;
            int sel = which >> 1;              // 0 = den, 1 = num
            part[((size_t)blockIdx.y * BD + b*512 + n0 + c2) * 2 + sel] = s;
        }
    }
}

// ---------------------------------------------------------------------------
// fused_window: LDS-staged E-tile + inline chunk-prefix reduction + register
// window ring.  Grid (BD/64, T/CH) = (16, 64) = 1024 blocks.
// FIX (r8): the cumsum correction previously used ring[u - s0] with runtime
// s0 -> compiler demoted ring[39] to scratch (VGPR=60, WRITE_SIZE 84MB).
// Replaced with a wave-uniform 4-way branch on sg so every ring index is a
// compile-time constant -> ring stays in VGPRs (rule #20).
// ---------------------------------------------------------------------------
__global__ __launch_bounds__(256, 3) void fused_window(
    const float* __restrict__ qf, const float* __restrict__ ekn,
    const float* __restrict__ part, const float* __restrict__ pb,
    __hip_bfloat16* __restrict__ yb)
{
    __shared__ float Et[64 * 64 * 2];     // 32 KB: [u][c] f32x2
    __shared__ float wl[CH][SS];          // 4 KB
    __shared__ float red[4 * 64 * 2];     // 2 KB
    const int tid = threadIdx.x;
    const int chunk = blockIdx.y;
    const int t0 = chunk * CH;
    const int col0 = blockIdx.x * 64;
    const int c = tid & 63;
    const int sg = tid >> 6;              // wave = s-group
    const int s0 = sg * 8;

    // Stage E tile: thread covers 16B (2 cols) of row u = (tid>>5) + j*8
    {
        const int cp = tid & 31;          // col-pair
        #pragma unroll
        for (int j = 0; j < 8; ++j) {
            int u = (tid >> 5) + j * 8;
            int t = t0 - 32 + u;
            if (t >= 0) {                 // wave-uniform (chunk==0: skips j<4)
                const void* g = (const void*)(ekn + ((size_t)t * BD + col0 + cp * 2) * 2);
                async_copy16((char*)Et + (tid >> 6) * 1024 + j * 4096, g);
            }
        }
        if (chunk == 0) {                 // zero rows 0..31 (t<0)
            f32x4 z = {0.f, 0.f, 0.f, 0.f};
            #pragma unroll
            for (int j = 0; j < 4; ++j)
                *(f32x4*)((char*)Et + tid * 16 + j * 4096) = z;
        }
    }

    // wl[t_local][j] = valid * exp(pb[t, t-31+j])
    #pragma unroll
    for (int i = 0; i < (CH * SS) / 256; ++i) {
        int idx = tid + i * 256;
        int tl = idx >> 5, jj = idx & 31;
        int t = t0 + tl;
        int u2 = t - (SS - 1) + jj;
        float w = 0.f;
        if (u2 >= 0) w = expf(pb[(size_t)t * TT + u2]);
        wl[tl][jj] = w;
    }

    // qv (sigmoid already applied) + inline chunk-prefix partial
    float qv[8];
    #pragma unroll
    for (int k = 0; k < 8; ++k)
        qv[k] = qf[(size_t)(t0 + s0 + k) * BD + col0 + c];
    f32x2 acc2 = {0.f, 0.f};
    #pragma unroll
    for (int j = 0; j < 16; ++j) {
        int p = sg + 4 * j;
        if (p < chunk)                    // wave-uniform predicate
            acc2 += *(const f32x2*)&part[((size_t)p * BD + col0 + c) * 2];
    }
    *(f32x2*)&red[(sg * 64 + c) * 2] = acc2;

    __syncthreads();                      // drains copies + wl + red

    f32x2 P = *(const f32x2*)&red[(0 * 64 + c) * 2];
    P += *(const f32x2*)&red[(1 * 64 + c) * 2];
    P += *(const f32x2*)&red[(2 * 64 + c) * 2];
    P += *(const f32x2*)&red[(3 * 64 + c) * 2];

    // Pull rows s0+1 .. s0+39 once into registers (ALL indices static)
    f32x2 ring[39];
    #pragma unroll
    for (int i = 0; i < 39; ++i)
        ring[i] = *(const f32x2*)&Et[((s0 + 1 + i) * 64 + c) * 2];

    // cs(s0) = P - sum_{u=s0+1}^{31} E[u]  -> ring indices 0..30-s0.
    // Wave-uniform branch on sg keeps every index compile-time constant.
    f32x2 cs = P;
    if (sg == 0) {
        #pragma unroll
        for (int i = 0; i < 31; ++i) cs -= ring[i];
    } else if (sg == 1) {
        #pragma unroll
        for (int i = 0; i < 23; ++i) cs -= ring[i];
    } else if (sg == 2) {
        #pragma unroll
        for (int i = 0; i < 15; ++i) cs -= ring[i];
    } else {
        #pragma unroll
        for (int i = 0; i < 7; ++i) cs -= ring[i];
    }

    #pragma unroll
    for (int k = 0; k < 8; ++k) {
        int s = s0 + k;
        if (k > 0) cs += ring[k - 1];
        f32x2 acc = cs;
        #pragma unroll
        for (int j4 = 0; j4 < 8; ++j4) {
            float4 w4 = *(const float4*)&wl[s][j4 * 4];
            acc += w4.x * ring[k + j4*4 + 0];
            acc += w4.y * ring[k + j4*4 + 1];
            acc += w4.z * ring[k + j4*4 + 2];
            acc += w4.w * ring[k + j4*4 + 3];
        }
        yb[(size_t)(t0 + s) * BD + col0 + c] = __float2bfloat16(qv[k] * acc.y / acc.x);
    }
}

// out = yb@Wo^T + bo.  Both operands bf16, 3-deep global_load_lds pipeline
// (verified structure from round 1).
__global__ __launch_bounds__(256) void gemm_out(
    const __hip_bfloat16* __restrict__ yb, const __hip_bfloat16* __restrict__ Wob,
    const float* __restrict__ bo, float* __restrict__ out)
{
    __shared__ char smem[24576];          // 3 buffers of 8KB
    const int tid = threadIdx.x;
    const int lane = tid & 63;
    const int wv = tid >> 6;
    const int wave_m = wv >> 1, wave_n = wv & 1;
    const int m0 = blockIdx.y * 64, n0 = blockIdx.x * 64;
    const int kq = lane >> 4, rr = lane & 15;

    f32x4 acc[2][2] = {};
    const __hip_bfloat16* Arow = yb + (size_t)(m0 + lane) * DD + wv * 8;
    const __hip_bfloat16* Wrow = Wob + (size_t)(n0 + lane) * DD + wv * 8;

    async_copy16(smem + 0*8192 +        wv*1024, Arow + 0);
    async_copy16(smem + 0*8192 + 4096 + wv*1024, Wrow + 0);
    async_copy16(smem + 1*8192 +        wv*1024, Arow + 32);
    async_copy16(smem + 1*8192 + 4096 + wv*1024, Wrow + 32);
    asm volatile("s_waitcnt vmcnt(2)" ::: "memory");
    __builtin_amdgcn_s_barrier();
    #pragma unroll
    for (int it = 0; it < 16; ++it) {
        if (it + 2 < 16) {
            char* nb = smem + ((it + 2) % 3) * 8192;
            async_copy16(nb +        wv*1024, Arow + (it+2)*32);
            async_copy16(nb + 4096 + wv*1024, Wrow + (it+2)*32);
        }
        const char* cb = smem + (it % 3) * 8192;
        bf16x8 a0 = *(const bf16x8*)(cb + kq*1024 + (wave_m*32 +  0 + rr)*16);
        bf16x8 a1 = *(const bf16x8*)(cb + kq*1024 + (wave_m*32 + 16 + rr)*16);
        bf16x8 w0 = *(const bf16x8*)(cb + 4096 + kq*1024 + (wave_n*32 +  0 + rr)*16);
        bf16x8 w1 = *(const bf16x8*)(cb + 4096 + kq*1024 + (wave_n*32 + 16 + rr)*16);
        acc[0][0] = MFMA16(a0, w0, acc[0][0]);
        acc[0][1] = MFMA16(a0, w1, acc[0][1]);
        acc[1][0] = MFMA16(a1, w0, acc[1][0]);
        acc[1][1] = MFMA16(a1, w1, acc[1][1]);
        if (it < 15) {
            if (it < 14) asm volatile("s_waitcnt vmcnt(2) lgkmcnt(0)" ::: "memory");
            else         asm volatile("s_waitcnt vmcnt(0) lgkmcnt(0)" ::: "memory");
            __builtin_amdgcn_s_barrier();
        }
    }
    #pragma unroll
    for (int ms = 0; ms < 2; ++ms)
        #pragma unroll
        for (int ns = 0; ns < 2; ++ns) {
            int n = n0 + wave_n*32 + ns*16 + rr;
            float bn = bo[n];
            #pragma unroll
            for (int r = 0; r < 4; ++r) {
                int m = m0 + wave_m*32 + ms*16 + kq*4 + r;
                out[(size_t)m * DD + n] = acc[ms][ns][r] + bn;
            }
        }
}

extern "C" void kernel_launch(void* const* d_in, const int* in_sizes, int n_in,
                              void* d_out, int out_size, void* d_ws, size_t ws_size,
                              hipStream_t stream) {
    const float* query = (const float*)d_in[0];
    const float* key   = (const float*)d_in[1];
    const float* value = (const float*)d_in[2];
    const float* Wq    = (const float*)d_in[3];
    const float* bq    = (const float*)d_in[4];
    const float* Wk    = (const float*)d_in[5];
    const float* bk    = (const float*)d_in[6];
    const float* Wv    = (const float*)d_in[7];
    const float* bv    = (const float*)d_in[8];
    const float* pb    = (const float*)d_in[9];
    const float* Wo    = (const float*)d_in[10];
    const float* bo    = (const float*)d_in[11];
    float* out = (float*)d_out;

    float* ws = (float*)d_ws;
    float* qf   = ws;                         // NE (sigmoid(q))
    float* ekn  = ws + (size_t)NE;            // 2*NE (interleaved {den,num})
    float* part = ws + (size_t)3 * NE;        // 2*64*1024 = 131072
    __hip_bfloat16* bfb = (__hip_bfloat16*)(part + 131072);
    __hip_bfloat16* qb  = bfb;                // NE each
    __hip_bfloat16* kb  = bfb + (size_t)NE;
    __hip_bfloat16* vb  = bfb + (size_t)2 * NE;
    __hip_bfloat16* yb  = bfb + (size_t)3 * NE;
    __hip_bfloat16* Wqb = bfb + (size_t)4 * NE;   // 262144 each
    __hip_bfloat16* Wkb = Wqb + 262144;
    __hip_bfloat16* Wvb = Wkb + 262144;
    __hip_bfloat16* Wob = Wvb + 262144;

    cast_all<<<7168, 256, 0, stream>>>(query, key, value, Wq, Wk, Wv, Wo,
                                       qb, kb, vb, Wqb, Wkb, Wvb, Wob);

    gemm_qkv<<<dim3(DD / 64, MR / 64, 2), 256, 0, stream>>>(
        qb, kb, vb, Wqb, Wkb, Wvb, bq, bk, bv,
        qf, ekn, part);

    fused_window<<<dim3(BD / 64, TT / CH), 256, 0, stream>>>(
        qf, ekn, part, pb, yb);

    gemm_out<<<dim3(DD / 64, MR / 64), 256, 0, stream>>>(yb, Wob, bo, out);
}

// Round 9
// 153.320 us; speedup vs baseline: 3.0833x; 1.0145x over previous
//
#include <hip/hip_runtime.h>
#include <hip/hip_bf16.h>

// Problem constants (AFTLocalAutoregressive): T=2048, B=2, D=512, S=32
#define TT 2048
#define BB 2
#define DD 512
#define BD (BB*DD)        // 1024 columns (b,d flattened)
#define SS 32
#define MR (TT*BB)        // 4096 GEMM rows; m = 2t + b
#define NE (TT*BB*DD)     // 2097152 elements per (T,B,D) tensor
#define CH 32             // t-chunk size for scan/window (== one 64-row m-tile)

typedef __bf16 bf16x8 __attribute__((ext_vector_type(8)));
typedef float f32x4 __attribute__((ext_vector_type(4)));
typedef float f32x2 __attribute__((ext_vector_type(2)));

__device__ __forceinline__ void async_copy16(void* lds, const void* gptr) {
    __builtin_amdgcn_global_load_lds(
        (const __attribute__((address_space(1))) void*)gptr,
        (__attribute__((address_space(3))) void*)lds,
        16, 0, 0);
}

#define MFMA16(a,b,c) __builtin_amdgcn_mfma_f32_16x16x32_bf16((a),(b),(c),0,0,0)

// fp32 -> bf16: blocks 0..6143 cover query/key/value; 6144..7167 cover 4 weights
__global__ __launch_bounds__(256) void cast_all(
    const float* __restrict__ s0, const float* __restrict__ s1, const float* __restrict__ s2,
    const float* __restrict__ w0, const float* __restrict__ w1,
    const float* __restrict__ w2, const float* __restrict__ w3,
    __hip_bfloat16* __restrict__ d0, __hip_bfloat16* __restrict__ d1, __hip_bfloat16* __restrict__ d2,
    __hip_bfloat16* __restrict__ e0, __hip_bfloat16* __restrict__ e1,
    __hip_bfloat16* __restrict__ e2, __hip_bfloat16* __restrict__ e3)
{
    int b = blockIdx.x;
    const float* s;
    __hip_bfloat16* d;
    size_t i;
    if (b < 6144) {
        int which = b >> 11;
        s = which == 0 ? s0 : (which == 1 ? s1 : s2);
        d = which == 0 ? d0 : (which == 1 ? d1 : d2);
        i = ((size_t)(b & 2047) * 256 + threadIdx.x) * 4;
    } else {
        int b2 = b - 6144;
        int which = b2 >> 8;
        s = which == 0 ? w0 : (which == 1 ? w1 : (which == 2 ? w2 : w3));
        d = which == 0 ? e0 : (which == 1 ? e1 : (which == 2 ? e2 : e3));
        i = ((size_t)(b2 & 255) * 256 + threadIdx.x) * 4;
    }
    float4 f = *(const float4*)(s + i);
    union { __hip_bfloat16 h[4]; ushort4 u; } cv;
    cv.h[0] = __float2bfloat16(f.x); cv.h[1] = __float2bfloat16(f.y);
    cv.h[2] = __float2bfloat16(f.z); cv.h[3] = __float2bfloat16(f.w);
    *(ushort4*)((unsigned short*)d + i) = cv.u;
}

// ---------------------------------------------------------------------------
// z=0: qf = sigmoid(query@Wq^T + bq)  (fp32 out; sigmoid folded in)
// z=1: k,v projections fused; epilogue writes interleaved ekn = {ek, ek*v}
//      AND per-chunk column sums part.
// XCD-aware tile remap (r9): dispatch-linear id %8 == blockIdx.x, so the 8
// blocks sharing an A-panel (same m-tile) used to land on 8 different XCDs
// -> 8x HBM refetch of A.  flat = bx + 8*by; mt = flat&63; nt = flat>>6
// puts all 8 n-blocks of one m-tile on ONE XCD (flat%8 == mt%8) -> A-panel
// fetched ~once.  Bijective; W-panels are L2-resident per XCD (0.5MB).
// 3-deep global_load_lds pipeline with counted vmcnt (verified r1/r8).
// ---------------------------------------------------------------------------
__global__ __launch_bounds__(256) void gemm_qkv(
    const __hip_bfloat16* __restrict__ qb, const __hip_bfloat16* __restrict__ kb,
    const __hip_bfloat16* __restrict__ vb,
    const __hip_bfloat16* __restrict__ Wqb, const __hip_bfloat16* __restrict__ Wkb,
    const __hip_bfloat16* __restrict__ Wvb,
    const float* __restrict__ bq, const float* __restrict__ bk,
    const float* __restrict__ bv,
    float* __restrict__ qout, float* __restrict__ ekn,
    float* __restrict__ part)
{
    __shared__ char smem[49152];          // 3 buffers (z=1: 16KB each, z=0: 8KB)
    const int tid = threadIdx.x;
    const int lane = tid & 63;
    const int wv = tid >> 6;
    const int wave_m = wv >> 1, wave_n = wv & 1;
    const int flat = blockIdx.x + 8 * blockIdx.y;   // 0..511
    const int mt = flat & 63, nt = flat >> 6;       // XCD = flat%8 = mt%8
    const int m0 = mt * 64, n0 = nt * 64;
    const int kq = lane >> 4, rr = lane & 15;

    if (blockIdx.z == 0) {
        f32x4 acc[2][2] = {};
        const __hip_bfloat16* Arow = qb + (size_t)(m0 + lane) * DD + wv * 8;
        const __hip_bfloat16* Wrow = Wqb + (size_t)(n0 + lane) * DD + wv * 8;
        async_copy16(smem + 0*8192 +        wv*1024, Arow + 0);
        async_copy16(smem + 0*8192 + 4096 + wv*1024, Wrow + 0);
        async_copy16(smem + 1*8192 +        wv*1024, Arow + 32);
        async_copy16(smem + 1*8192 + 4096 + wv*1024, Wrow + 32);
        asm volatile("s_waitcnt vmcnt(2)" ::: "memory");   // tile 0 landed
        __builtin_amdgcn_s_barrier();
        #pragma unroll
        for (int it = 0; it < 16; ++it) {
            if (it + 2 < 16) {
                char* nb = smem + ((it + 2) % 3) * 8192;
                async_copy16(nb +        wv*1024, Arow + (it+2)*32);
                async_copy16(nb + 4096 + wv*1024, Wrow + (it+2)*32);
            }
            const char* cb = smem + (it % 3) * 8192;
            bf16x8 a0 = *(const bf16x8*)(cb + kq*1024 + (wave_m*32 +  0 + rr)*16);
            bf16x8 a1 = *(const bf16x8*)(cb + kq*1024 + (wave_m*32 + 16 + rr)*16);
            bf16x8 w0 = *(const bf16x8*)(cb + 4096 + kq*1024 + (wave_n*32 +  0 + rr)*16);
            bf16x8 w1 = *(const bf16x8*)(cb + 4096 + kq*1024 + (wave_n*32 + 16 + rr)*16);
            acc[0][0] = MFMA16(a0, w0, acc[0][0]);
            acc[0][1] = MFMA16(a0, w1, acc[0][1]);
            acc[1][0] = MFMA16(a1, w0, acc[1][0]);
            acc[1][1] = MFMA16(a1, w1, acc[1][1]);
            if (it < 15) {
                if (it < 14) asm volatile("s_waitcnt vmcnt(2) lgkmcnt(0)" ::: "memory");
                else         asm volatile("s_waitcnt vmcnt(0) lgkmcnt(0)" ::: "memory");
                __builtin_amdgcn_s_barrier();
            }
        }
        #pragma unroll
        for (int ms = 0; ms < 2; ++ms)
            #pragma unroll
            for (int ns = 0; ns < 2; ++ns) {
                int n = n0 + wave_n*32 + ns*16 + rr;
                float bn = bq[n];
                #pragma unroll
                for (int r = 0; r < 4; ++r) {
                    int m = m0 + wave_m*32 + ms*16 + kq*4 + r;
                    float x = acc[ms][ns][r] + bn;
                    qout[(size_t)m * DD + n] = 1.f / (1.f + expf(-x));  // sigmoid folded
                }
            }
    } else {
        f32x4 acck[2][2] = {}, accv[2][2] = {};
        const __hip_bfloat16* AKrow = kb + (size_t)(m0 + lane) * DD + wv * 8;
        const __hip_bfloat16* WKrow = Wkb + (size_t)(n0 + lane) * DD + wv * 8;
        const __hip_bfloat16* AVrow = vb + (size_t)(m0 + lane) * DD + wv * 8;
        const __hip_bfloat16* WVrow = Wvb + (size_t)(n0 + lane) * DD + wv * 8;
        #pragma unroll
        for (int pt = 0; pt < 2; ++pt) {
            char* nb = smem + pt * 16384;
            async_copy16(nb +         wv*1024, AKrow + pt*32);
            async_copy16(nb +  4096 + wv*1024, WKrow + pt*32);
            async_copy16(nb +  8192 + wv*1024, AVrow + pt*32);
            async_copy16(nb + 12288 + wv*1024, WVrow + pt*32);
        }
        asm volatile("s_waitcnt vmcnt(4)" ::: "memory");   // tile 0 landed
        __builtin_amdgcn_s_barrier();
        #pragma unroll
        for (int it = 0; it < 16; ++it) {
            if (it + 2 < 16) {
                char* nb = smem + ((it + 2) % 3) * 16384;
                async_copy16(nb +         wv*1024, AKrow + (it+2)*32);
                async_copy16(nb +  4096 + wv*1024, WKrow + (it+2)*32);
                async_copy16(nb +  8192 + wv*1024, AVrow + (it+2)*32);
                async_copy16(nb + 12288 + wv*1024, WVrow + (it+2)*32);
            }
            const char* cb = smem + (it % 3) * 16384;
            bf16x8 ak0 = *(const bf16x8*)(cb +         kq*1024 + (wave_m*32 +  0 + rr)*16);
            bf16x8 ak1 = *(const bf16x8*)(cb +         kq*1024 + (wave_m*32 + 16 + rr)*16);
            bf16x8 bk0 = *(const bf16x8*)(cb +  4096 + kq*1024 + (wave_n*32 +  0 + rr)*16);
            bf16x8 bk1 = *(const bf16x8*)(cb +  4096 + kq*1024 + (wave_n*32 + 16 + rr)*16);
            bf16x8 av0 = *(const bf16x8*)(cb +  8192 + kq*1024 + (wave_m*32 +  0 + rr)*16);
            bf16x8 av1 = *(const bf16x8*)(cb +  8192 + kq*1024 + (wave_m*32 + 16 + rr)*16);
            bf16x8 bv0 = *(const bf16x8*)(cb + 12288 + kq*1024 + (wave_n*32 +  0 + rr)*16);
            bf16x8 bv1 = *(const bf16x8*)(cb + 12288 + kq*1024 + (wave_n*32 + 16 + rr)*16);
            acck[0][0] = MFMA16(ak0, bk0, acck[0][0]);
            acck[0][1] = MFMA16(ak0, bk1, acck[0][1]);
            acck[1][0] = MFMA16(ak1, bk0, acck[1][0]);
            acck[1][1] = MFMA16(ak1, bk1, acck[1][1]);
            accv[0][0] = MFMA16(av0, bv0, accv[0][0]);
            accv[0][1] = MFMA16(av0, bv1, accv[0][1]);
            accv[1][0] = MFMA16(av1, bv0, accv[1][0]);
            accv[1][1] = MFMA16(av1, bv1, accv[1][1]);
            if (it < 15) {
                if (it < 14) asm volatile("s_waitcnt vmcnt(4) lgkmcnt(0)" ::: "memory");
                else         asm volatile("s_waitcnt vmcnt(0) lgkmcnt(0)" ::: "memory");
                __builtin_amdgcn_s_barrier();
            }
        }
        // epilogue: interleaved ekn stores + per-chunk column sums (b = r&1)
        float sd[2][2] = {{0.f,0.f},{0.f,0.f}};   // [ns][parity]
        float sn[2][2] = {{0.f,0.f},{0.f,0.f}};
        #pragma unroll
        for (int ms = 0; ms < 2; ++ms)
            #pragma unroll
            for (int ns = 0; ns < 2; ++ns) {
                int n = n0 + wave_n*32 + ns*16 + rr;
                float bkn = bk[n], bvn = bv[n];
                #pragma unroll
                for (int r = 0; r < 4; ++r) {
                    int m = m0 + wave_m*32 + ms*16 + kq*4 + r;
                    float e  = expf(acck[ms][ns][r] + bkn);
                    float nv = e * (accv[ms][ns][r] + bvn);
                    float2 st; st.x = e; st.y = nv;
                    *(float2*)&ekn[((size_t)m * DD + n) * 2] = st;
                    sd[ns][r & 1] += e;
                    sn[ns][r & 1] += nv;
                }
            }
        #pragma unroll
        for (int ns = 0; ns < 2; ++ns)
            #pragma unroll
            for (int par = 0; par < 2; ++par) {
                sd[ns][par] += __shfl_xor(sd[ns][par], 16, 64);
                sd[ns][par] += __shfl_xor(sd[ns][par], 32, 64);
                sn[ns][par] += __shfl_xor(sn[ns][par], 16, 64);
                sn[ns][par] += __shfl_xor(sn[ns][par], 32, 64);
            }
        __syncthreads();                       // smem free for reuse
        float* red = (float*)smem;             // red[which(4)][wave_m(2)][64]
        if (lane < 16) {
            #pragma unroll
            for (int ns = 0; ns < 2; ++ns) {
                int c2 = wave_n*32 + ns*16 + rr;
                red[(0*2 + wave_m)*64 + c2] = sd[ns][0];
                red[(1*2 + wave_m)*64 + c2] = sd[ns][1];
                red[(2*2 + wave_m)*64 + c2] = sn[ns][0];
                red[(3*2 + wave_m)*64 + c2] = sn[ns][1];
            }
        }
        __syncthreads();
        {
            int which = tid >> 6;              // 0: d,b0  1: d,b1  2: n,b0  3: n,b1
            int c2 = tid & 63;
            float s = red[(which*2 + 0)*64 + c2] + red[(which*2 + 1)*64 + c2];
            int b = which & 1;
            int sel = which >> 1;              // 0 = den, 1 = num
            part[((size_t)mt * BD + b*512 + n0 + c2) * 2 + sel] = s;
        }
    }
}

// ---------------------------------------------------------------------------
// fused_window: LDS-staged E-tile + inline chunk-prefix reduction + register
// window ring.  Grid (BD/64, T/CH) = (16, 64).  All ring indices static
// (r8 fix, rule #20) -> ring lives in VGPRs.  qf holds sigmoid(q).
// ---------------------------------------------------------------------------
__global__ __launch_bounds__(256, 3) void fused_window(
    const float* __restrict__ qf, const float* __restrict__ ekn,
    const float* __restrict__ part, const float* __restrict__ pb,
    __hip_bfloat16* __restrict__ yb)
{
    __shared__ float Et[64 * 64 * 2];     // 32 KB: [u][c] f32x2
    __shared__ float wl[CH][SS];          // 4 KB
    __shared__ float red[4 * 64 * 2];     // 2 KB
    const int tid = threadIdx.x;
    const int chunk = blockIdx.y;
    const int t0 = chunk * CH;
    const int col0 = blockIdx.x * 64;
    const int c = tid & 63;
    const int sg = tid >> 6;              // wave = s-group
    const int s0 = sg * 8;

    // Stage E tile: thread covers 16B (2 cols) of row u = (tid>>5) + j*8
    {
        const int cp = tid & 31;          // col-pair
        #pragma unroll
        for (int j = 0; j < 8; ++j) {
            int u = (tid >> 5) + j * 8;
            int t = t0 - 32 + u;
            if (t >= 0) {                 // wave-uniform (chunk==0: skips j<4)
                const void* g = (const void*)(ekn + ((size_t)t * BD + col0 + cp * 2) * 2);
                async_copy16((char*)Et + (tid >> 6) * 1024 + j * 4096, g);
            }
        }
        if (chunk == 0) {                 // zero rows 0..31 (t<0)
            f32x4 z = {0.f, 0.f, 0.f, 0.f};
            #pragma unroll
            for (int j = 0; j < 4; ++j)
                *(f32x4*)((char*)Et + tid * 16 + j * 4096) = z;
        }
    }

    // wl[t_local][j] = valid * exp(pb[t, t-31+j])
    #pragma unroll
    for (int i = 0; i < (CH * SS) / 256; ++i) {
        int idx = tid + i * 256;
        int tl = idx >> 5, jj = idx & 31;
        int t = t0 + tl;
        int u2 = t - (SS - 1) + jj;
        float w = 0.f;
        if (u2 >= 0) w = expf(pb[(size_t)t * TT + u2]);
        wl[tl][jj] = w;
    }

    // qv (sigmoid already applied) + inline chunk-prefix partial
    float qv[8];
    #pragma unroll
    for (int k = 0; k < 8; ++k)
        qv[k] = qf[(size_t)(t0 + s0 + k) * BD + col0 + c];
    f32x2 acc2 = {0.f, 0.f};
    #pragma unroll
    for (int j = 0; j < 16; ++j) {
        int p = sg + 4 * j;
        if (p < chunk)                    // wave-uniform predicate
            acc2 += *(const f32x2*)&part[((size_t)p * BD + col0 + c) * 2];
    }
    *(f32x2*)&red[(sg * 64 + c) * 2] = acc2;

    __syncthreads();                      // drains copies + wl + red

    f32x2 P = *(const f32x2*)&red[(0 * 64 + c) * 2];
    P += *(const f32x2*)&red[(1 * 64 + c) * 2];
    P += *(const f32x2*)&red[(2 * 64 + c) * 2];
    P += *(const f32x2*)&red[(3 * 64 + c) * 2];

    // Pull rows s0+1 .. s0+39 once into registers (ALL indices static)
    f32x2 ring[39];
    #pragma unroll
    for (int i = 0; i < 39; ++i)
        ring[i] = *(const f32x2*)&Et[((s0 + 1 + i) * 64 + c) * 2];

    // cs(s0) = P - sum_{u=s0+1}^{31} E[u]  -> ring indices 0..30-s0.
    // Wave-uniform branch on sg keeps every index compile-time constant.
    f32x2 cs = P;
    if (sg == 0) {
        #pragma unroll
        for (int i = 0; i < 31; ++i) cs -= ring[i];
    } else if (sg == 1) {
        #pragma unroll
        for (int i = 0; i < 23; ++i) cs -= ring[i];
    } else if (sg == 2) {
        #pragma unroll
        for (int i = 0; i < 15; ++i) cs -= ring[i];
    } else {
        #pragma unroll
        for (int i = 0; i < 7; ++i) cs -= ring[i];
    }

    #pragma unroll
    for (int k = 0; k < 8; ++k) {
        int s = s0 + k;
        if (k > 0) cs += ring[k - 1];
        f32x2 acc = cs;
        #pragma unroll
        for (int j4 = 0; j4 < 8; ++j4) {
            float4 w4 = *(const float4*)&wl[s][j4 * 4];
            acc += w4.x * ring[k + j4*4 + 0];
            acc += w4.y * ring[k + j4*4 + 1];
            acc += w4.z * ring[k + j4*4 + 2];
            acc += w4.w * ring[k + j4*4 + 3];
        }
        yb[(size_t)(t0 + s) * BD + col0 + c] = __float2bfloat16(qv[k] * acc.y / acc.x);
    }
}

// out = yb@Wo^T + bo.  Both operands bf16, 3-deep global_load_lds pipeline.
// XCD-aware tile remap (r9) as in gemm_qkv: yb A-panel fetched once per
// m-tile instead of 8x.
__global__ __launch_bounds__(256) void gemm_out(
    const __hip_bfloat16* __restrict__ yb, const __hip_bfloat16* __restrict__ Wob,
    const float* __restrict__ bo, float* __restrict__ out)
{
    __shared__ char smem[24576];          // 3 buffers of 8KB
    const int tid = threadIdx.x;
    const int lane = tid & 63;
    const int wv = tid >> 6;
    const int wave_m = wv >> 1, wave_n = wv & 1;
    const int flat = blockIdx.x + 8 * blockIdx.y;   // 0..511
    const int mt = flat & 63, nt = flat >> 6;       // XCD = flat%8 = mt%8
    const int m0 = mt * 64, n0 = nt * 64;
    const int kq = lane >> 4, rr = lane & 15;

    f32x4 acc[2][2] = {};
    const __hip_bfloat16* Arow = yb + (size_t)(m0 + lane) * DD + wv * 8;
    const __hip_bfloat16* Wrow = Wob + (size_t)(n0 + lane) * DD + wv * 8;

    async_copy16(smem + 0*8192 +        wv*1024, Arow + 0);
    async_copy16(smem + 0*8192 + 4096 + wv*1024, Wrow + 0);
    async_copy16(smem + 1*8192 +        wv*1024, Arow + 32);
    async_copy16(smem + 1*8192 + 4096 + wv*1024, Wrow + 32);
    asm volatile("s_waitcnt vmcnt(2)" ::: "memory");
    __builtin_amdgcn_s_barrier();
    #pragma unroll
    for (int it = 0; it < 16; ++it) {
        if (it + 2 < 16) {
            char* nb = smem + ((it + 2) % 3) * 8192;
            async_copy16(nb +        wv*1024, Arow + (it+2)*32);
            async_copy16(nb + 4096 + wv*1024, Wrow + (it+2)*32);
        }
        const char* cb = smem + (it % 3) * 8192;
        bf16x8 a0 = *(const bf16x8*)(cb + kq*1024 + (wave_m*32 +  0 + rr)*16);
        bf16x8 a1 = *(const bf16x8*)(cb + kq*1024 + (wave_m*32 + 16 + rr)*16);
        bf16x8 w0 = *(const bf16x8*)(cb + 4096 + kq*1024 + (wave_n*32 +  0 + rr)*16);
        bf16x8 w1 = *(const bf16x8*)(cb + 4096 + kq*1024 + (wave_n*32 + 16 + rr)*16);
        acc[0][0] = MFMA16(a0, w0, acc[0][0]);
        acc[0][1] = MFMA16(a0, w1, acc[0][1]);
        acc[1][0] = MFMA16(a1, w0, acc[1][0]);
        acc[1][1] = MFMA16(a1, w1, acc[1][1]);
        if (it < 15) {
            if (it < 14) asm volatile("s_waitcnt vmcnt(2) lgkmcnt(0)" ::: "memory");
            else         asm volatile("s_waitcnt vmcnt(0) lgkmcnt(0)" ::: "memory");
            __builtin_amdgcn_s_barrier();
        }
    }
    #pragma unroll
    for (int ms = 0; ms < 2; ++ms)
        #pragma unroll
        for (int ns = 0; ns < 2; ++ns) {
            int n = n0 + wave_n*32 + ns*16 + rr;
            float bn = bo[n];
            #pragma unroll
            for (int r = 0; r < 4; ++r) {
                int m = m0 + wave_m*32 + ms*16 + kq*4 + r;
                out[(size_t)m * DD + n] = acc[ms][ns][r] + bn;
            }
        }
}

extern "C" void kernel_launch(void* const* d_in, const int* in_sizes, int n_in,
                              void* d_out, int out_size, void* d_ws, size_t ws_size,
                              hipStream_t stream) {
    const float* query = (const float*)d_in[0];
    const float* key   = (const float*)d_in[1];
    const float* value = (const float*)d_in[2];
    const float* Wq    = (const float*)d_in[3];
    const float* bq    = (const float*)d_in[4];
    const float* Wk    = (const float*)d_in[5];
    const float* bk    = (const float*)d_in[6];
    const float* Wv    = (const float*)d_in[7];
    const float* bv    = (const float*)d_in[8];
    const float* pb    = (const float*)d_in[9];
    const float* Wo    = (const float*)d_in[10];
    const float* bo    = (const float*)d_in[11];
    float* out = (float*)d_out;

    float* ws = (float*)d_ws;
    float* qf   = ws;                         // NE (sigmoid(q))
    float* ekn  = ws + (size_t)NE;            // 2*NE (interleaved {den,num})
    float* part = ws + (size_t)3 * NE;        // 2*64*1024 = 131072
    __hip_bfloat16* bfb = (__hip_bfloat16*)(part + 131072);
    __hip_bfloat16* qb  = bfb;                // NE each
    __hip_bfloat16* kb  = bfb + (size_t)NE;
    __hip_bfloat16* vb  = bfb + (size_t)2 * NE;
    __hip_bfloat16* yb  = bfb + (size_t)3 * NE;
    __hip_bfloat16* Wqb = bfb + (size_t)4 * NE;   // 262144 each
    __hip_bfloat16* Wkb = Wqb + 262144;
    __hip_bfloat16* Wvb = Wkb + 262144;
    __hip_bfloat16* Wob = Wvb + 262144;

    cast_all<<<7168, 256, 0, stream>>>(query, key, value, Wq, Wk, Wv, Wo,
                                       qb, kb, vb, Wqb, Wkb, Wvb, Wob);

    gemm_qkv<<<dim3(DD / 64, MR / 64, 2), 256, 0, stream>>>(
        qb, kb, vb, Wqb, Wkb, Wvb, bq, bk, bv,
        qf, ekn, part);

    fused_window<<<dim3(BD / 64, TT / CH), 256, 0, stream>>>(
        qf, ekn, part, pb, yb);

    gemm_out<<<dim3(DD / 64, MR / 64), 256, 0, stream>>>(yb, Wob, bo, out);
}